// Round 4
// baseline (724.234 us; speedup 1.0000x reference)
//
#include <hip/hip_runtime.h>
#include <math.h>

// Problem geometry: D=256 fixed; N, K from in_sizes.
#define D      256
#define D4     64
#define TAU    6.0e-3f   // near-tie margin; bf16-3-slice score error ~2e-3

// ---- MFMA-path geometry ----
#define KPAD    4096     // padded subsampled-codebook size
#define NSPLIT  4        // entry splits (kb = blockIdx.x & 3)
#define KSPAN   1024     // entries per split
#define TNE     256      // entry tile
#define TMTOK   128      // token tile
#define KPK     768      // packed K'' = 3 slices of 256 (hh, hl, lh)
#define BK      32       // staged K'' chunk
#define NCHUNK  24       // chunks per tile (KPK/BK)
#define NTILE   4        // entry tiles per split (KSPAN/TNE)
#define NSTEP   96       // NTILE*NCHUNK
#define BUFU    12288    // ushorts per LDS buffer: A 16*512 + B 8*512 (24 KiB)

typedef short bf16x8 __attribute__((ext_vector_type(8)));
typedef float f32x16 __attribute__((ext_vector_type(16)));

#define GLD16(g, l) __builtin_amdgcn_global_load_lds( \
    (const __attribute__((address_space(1))) void*)(g), \
    (__attribute__((address_space(3))) void*)(l), 16, 0, 0)

__device__ inline ushort f2bf_rn(float f) {           // RNE f32 -> bf16 bits
    unsigned u = __float_as_uint(f);
    unsigned r = (u + 0x7fffu + ((u >> 16) & 1u)) >> 16;
    return (ushort)r;
}
__device__ inline float bf2f(ushort u) { return __uint_as_float(((unsigned)u) << 16); }
__device__ inline f32x16 zero16() {
    f32x16 z = {0,0,0,0,0,0,0,0,0,0,0,0,0,0,0,0};
    return z;
}

// ---------------------------------------------------------------------------
// p01: fused prep. Wave-id < Ntok: xpack[t][512] = [bf16hi | bf16lo] of x_t.
// Else: cpack[k][512] likewise (zeros for pads) + c2[k] (+inf for pads).
__global__ __launch_bounds__(256)
void p01_pack(const float4* __restrict__ x4, const float4* __restrict__ cb4,
              const int* __restrict__ ridx, ushort* __restrict__ xp,
              ushort* __restrict__ cp, float* __restrict__ c2,
              int Ntok, int K) {
    int id   = (int)(blockIdx.x * 4 + (threadIdx.x >> 6));
    int lane = threadIdx.x & 63;
    if (id < Ntok) {
        float4 v = x4[(size_t)id * D4 + lane];
        float f[4] = {v.x, v.y, v.z, v.w};
        ushort4 h, lo; ushort* hp = &h.x; ushort* lp = &lo.x;
        #pragma unroll
        for (int i = 0; i < 4; ++i) {
            ushort hb = f2bf_rn(f[i]);
            hp[i] = hb;
            lp[i] = f2bf_rn(f[i] - bf2f(hb));
        }
        *(ushort4*)&xp[(size_t)id * 512 + 4 * lane]       = h;
        *(ushort4*)&xp[(size_t)id * 512 + 256 + 4 * lane] = lo;
        return;
    }
    int k = id - Ntok;
    if (k >= KPAD) return;
    ushort4 h, lo; ushort* hp = &h.x; ushort* lp = &lo.x;
    double s = 0.0;
    if (k < K) {
        int row = ridx[k];
        float4 v = cb4[(size_t)row * D4 + lane];
        float f[4] = {v.x, v.y, v.z, v.w};
        #pragma unroll
        for (int i = 0; i < 4; ++i) {
            ushort hb = f2bf_rn(f[i]);
            hp[i] = hb;
            lp[i] = f2bf_rn(f[i] - bf2f(hb));
            s = fma((double)f[i], (double)f[i], s);
        }
    } else {
        hp[0]=hp[1]=hp[2]=hp[3]=0; lp[0]=lp[1]=lp[2]=lp[3]=0;
    }
    *(ushort4*)&cp[(size_t)k * 512 + 4 * lane]       = h;
    *(ushort4*)&cp[(size_t)k * 512 + 256 + 4 * lane] = lo;
    #pragma unroll
    for (int off = 32; off; off >>= 1) s += __shfl_xor(s, off, 64);
    if (lane == 0) c2[k] = (k < K) ? (float)s : INFINITY;
}

// ---------------------------------------------------------------------------
// k1_mfma: 3-deep software pipeline. Per step s (of 96 = 4 tiles x 24 chunks):
//   stage(s+2) -> vmcnt(12) [waits stage(s) only] -> s_barrier ->
//   ds_read frags(s) -> lgkmcnt(0) -> s_barrier [buf s reusable] -> 16 MFMA.
// Loads for steps s+1, s+2 stay in flight across barriers (T4 counted vmcnt).
__global__ __launch_bounds__(256, 2)
void k1_mfma(const ushort* __restrict__ xp, const ushort* __restrict__ cp,
             const float* __restrict__ c2,
             float* __restrict__ pb1, float* __restrict__ pb2,
             int* __restrict__ pbi, int Ntok) {
    __shared__ __align__(16) ushort lds[3 * BUFU];   // 72 KiB
    __shared__ float c2all[NTILE * TNE];             // 4 KiB

    const int tid  = threadIdx.x;
    const int w    = tid >> 6;
    const int lane = tid & 63;
    const int we   = w >> 1;           // entry half (128 entries)
    const int wn   = w & 1;            // token half (64 tokens)
    const int hi   = lane >> 5;
    const int l31  = lane & 31;

    const int kb  = (int)(blockIdx.x & (NSPLIT - 1));
    const int m0  = (int)(blockIdx.x >> 2) * TMTOK;
    const int e0s = kb * KSPAN;

    #pragma unroll
    for (int i = 0; i < 4; ++i) c2all[i * 256 + tid] = c2[e0s + i * 256 + tid];

    auto stage = [&](int s, int buf) {
        const int tile  = s / NCHUNK;
        const int chunk = s - tile * NCHUNK;
        const int e0    = e0s + tile * TNE;
        const int kcol0 = chunk * BK + hi * 8;
        ushort* A = &lds[buf * BUFU];
        ushort* B = &lds[buf * BUFU + 8192];
        #pragma unroll
        for (int j = 0; j < 4; ++j) {                 // A: 16 groups / 4 waves
            int p = w * 4 + j, kc = p >> 3, g = p & 7;
            int krow = e0 + g * 32 + l31;
            int kcol = kcol0 + kc * 16;
            int srck = (((kcol >> 8) == 1) ? 256 : 0) + (kcol & 255);
            GLD16(cp + (size_t)krow * 512 + srck, &A[p * 512]);
        }
        #pragma unroll
        for (int j = 0; j < 2; ++j) {                 // B: 8 groups / 4 waves
            int q = w * 2 + j, kc = q >> 2, g = q & 3;
            int trow = m0 + g * 32 + l31;
            int kcol = kcol0 + kc * 16;
            int srck = (((kcol >> 8) == 2) ? 256 : 0) + (kcol & 255);
            GLD16(xp + (size_t)trow * 512 + srck, &B[q * 512]);
        }
    };

    float b1[2] = {INFINITY, INFINITY}, b2[2] = {INFINITY, INFINITY};
    int   bi[2] = {0, 0};
    f32x16 acc[4][2];
    #pragma unroll
    for (int mt = 0; mt < 4; ++mt)
        #pragma unroll
        for (int nt = 0; nt < 2; ++nt) acc[mt][nt] = zero16();

    stage(0, 0);
    stage(1, 1);

    int bufr = 0;
    for (int s = 0; s < NSTEP; ++s) {
        int sp = s + 2; if (sp >= NSTEP) sp = NSTEP - 1;   // tail clamp: counts uniform
        int bufc = bufr + 2; if (bufc >= 3) bufc -= 3;
        stage(sp, bufc);

        asm volatile("s_waitcnt vmcnt(12)" ::: "memory");  // stage(s) done, s+1/s+2 in flight
        __builtin_amdgcn_sched_barrier(0);
        __builtin_amdgcn_s_barrier();                      // all waves: buf[s] ready
        __builtin_amdgcn_sched_barrier(0);

        const ushort* A = &lds[bufr * BUFU];
        const ushort* B = &lds[bufr * BUFU + 8192];
        bf16x8 af[2][4], bfr[2][2];
        #pragma unroll
        for (int kc = 0; kc < 2; ++kc) {
            #pragma unroll
            for (int mt = 0; mt < 4; ++mt)
                af[kc][mt] = *(const bf16x8*)&A[(kc * 8 + we * 4 + mt) * 512 + lane * 8];
            #pragma unroll
            for (int nt = 0; nt < 2; ++nt)
                bfr[kc][nt] = *(const bf16x8*)&B[(kc * 4 + wn * 2 + nt) * 512 + lane * 8];
        }
        asm volatile("s_waitcnt lgkmcnt(0)" ::: "memory"); // frags in regs
        __builtin_amdgcn_sched_barrier(0);
        __builtin_amdgcn_s_barrier();                      // buf[s] free for overwrite
        __builtin_amdgcn_sched_barrier(0);

        __builtin_amdgcn_s_setprio(1);
        #pragma unroll
        for (int kc = 0; kc < 2; ++kc)
            #pragma unroll
            for (int mt = 0; mt < 4; ++mt)
                #pragma unroll
                for (int nt = 0; nt < 2; ++nt)
                    acc[mt][nt] = __builtin_amdgcn_mfma_f32_32x32x16_bf16(
                        af[kc][mt], bfr[kc][nt], acc[mt][nt], 0, 0, 0);
        __builtin_amdgcn_s_setprio(0);

        const int tile  = s / NCHUNK;
        const int chunk = s - tile * NCHUNK;
        if (chunk == NCHUNK - 1) {                         // per-tile epilogue
            #pragma unroll
            for (int nt = 0; nt < 2; ++nt)
                #pragma unroll
                for (int mt = 0; mt < 4; ++mt) {
                    #pragma unroll
                    for (int r = 0; r < 16; ++r) {
                        int rl = we * 128 + mt * 32 + (r & 3) + 8 * (r >> 2) + 4 * hi;
                        float sc = fmaf(-2.f, acc[mt][nt][r], c2all[tile * 256 + rl]);
                        int   k  = e0s + tile * 256 + rl;
                        bool better = (sc < b1[nt]) || (sc == b1[nt] && k < bi[nt]);
                        float nb2 = better ? b1[nt] : fminf(b2[nt], sc);
                        b1[nt] = better ? sc : b1[nt];
                        bi[nt] = better ? k  : bi[nt];
                        b2[nt] = nb2;
                    }
                    acc[mt][nt] = zero16();
                }
        }
        bufr = bufr + 1; if (bufr >= 3) bufr = 0;
    }

    // merge lane <-> lane^32 (complementary rows, same token col)
    #pragma unroll
    for (int nt = 0; nt < 2; ++nt) {
        float o1 = __shfl_xor(b1[nt], 32, 64);
        float o2 = __shfl_xor(b2[nt], 32, 64);
        int   oi = __shfl_xor(bi[nt], 32, 64);
        if (o1 < b1[nt] || (o1 == b1[nt] && oi < bi[nt])) {
            b2[nt] = fminf(b1[nt], o2); b1[nt] = o1; bi[nt] = oi;
        } else b2[nt] = fminf(b2[nt], o1);
    }

    __syncthreads();                       // drains tail loads; LDS reusable
    float* s1 = (float*)lds;               // [we][128 tokens]
    float* s2 = s1 + 256;
    int*   si = (int*)(s2 + 256);
    if (hi == 0) {
        #pragma unroll
        for (int nt = 0; nt < 2; ++nt) {
            int tl = wn * 64 + nt * 32 + l31;
            s1[we * 128 + tl] = b1[nt];
            s2[we * 128 + tl] = b2[nt];
            si[we * 128 + tl] = bi[nt];
        }
    }
    __syncthreads();
    if (tid < TMTOK) {
        float v1 = s1[tid], v2 = s2[tid]; int vi = si[tid];
        float u1 = s1[128 + tid], u2 = s2[128 + tid]; int ui = si[128 + tid];
        if (u1 < v1 || (u1 == v1 && ui < vi)) { v2 = fminf(v1, u2); v1 = u1; vi = ui; }
        else                                  { v2 = fminf(v2, u1); }
        size_t o = (size_t)kb * Ntok + m0 + tid;
        pb1[o] = v1; pb2[o] = v2; pbi[o] = vi;
    }
}

// ---------------------------------------------------------------------------
// k2: combine splits per token; write provisional global idx; flag near-ties.
__global__ __launch_bounds__(256)
void k2_combine(const float* __restrict__ pb1, const float* __restrict__ pb2,
                const int* __restrict__ pbi, const int* __restrict__ ridx,
                int* __restrict__ gidx, int* __restrict__ tlist,
                int* __restrict__ cnt, int Ntok, int nsplit) {
    int t = blockIdx.x * 256 + threadIdx.x;
    if (t >= Ntok) return;
    float v1 = INFINITY, v2 = INFINITY; int vi = 0x7fffffff;
    for (int kb = 0; kb < nsplit; ++kb) {
        size_t o = (size_t)kb * Ntok + t;
        float u1 = pb1[o], u2 = pb2[o]; int ui = pbi[o];
        if (u1 < v1 || (u1 == v1 && ui < vi)) { v2 = fminf(v1, u2); v1 = u1; vi = ui; }
        else                                  { v2 = fminf(v2, u1); }
    }
    gidx[t] = ridx[vi];
    if (v2 - v1 < TAU) {
        int pos = atomicAdd(cnt, 1);
        tlist[pos] = t;
    }
}

// ---------------------------------------------------------------------------
// k_recheck: exact f64 argmin with lexicographic tie-break for flagged tokens.
__global__ __launch_bounds__(256)
void k_recheck(const float4* __restrict__ x4, const float4* __restrict__ cb4,
               const int* __restrict__ ridx, const int* __restrict__ tlist,
               const int* __restrict__ cnt, int* __restrict__ gidx, int K) {
    __shared__ float4 xls[D4];
    __shared__ double rv[256];
    __shared__ int    rix[256];
    const int tid = threadIdx.x;
    const int n   = *cnt;
    for (int fi = blockIdx.x; fi < n; fi += gridDim.x) {
        int t = tlist[fi];
        if (tid < D4) xls[tid] = x4[(size_t)t * D4 + tid];
        __syncthreads();
        double bv = INFINITY; int bi = 0x7fffffff;
        for (int k = tid; k < K; k += 256) {
            const float4* cr = cb4 + (size_t)ridx[k] * D4;
            double s = 0.0, cc = 0.0;
            #pragma unroll 4
            for (int d = 0; d < D4; ++d) {
                float4 cv = cr[d], xv = xls[d];
                s  = fma((double)cv.x, (double)xv.x, s);
                s  = fma((double)cv.y, (double)xv.y, s);
                s  = fma((double)cv.z, (double)xv.z, s);
                s  = fma((double)cv.w, (double)xv.w, s);
                cc = fma((double)cv.x, (double)cv.x, cc);
                cc = fma((double)cv.y, (double)cv.y, cc);
                cc = fma((double)cv.z, (double)cv.z, cc);
                cc = fma((double)cv.w, (double)cv.w, cc);
            }
            double sc = cc - 2.0 * s;
            if (sc < bv || (sc == bv && k < bi)) { bv = sc; bi = k; }
        }
        rv[tid] = bv; rix[tid] = bi;
        __syncthreads();
        for (int st = 128; st; st >>= 1) {
            if (tid < st) {
                double u = rv[tid + st]; int ui = rix[tid + st];
                if (u < rv[tid] || (u == rv[tid] && ui < rix[tid])) {
                    rv[tid] = u; rix[tid] = ui;
                }
            }
            __syncthreads();
        }
        if (tid == 0) gidx[t] = ridx[rix[0]];
        __syncthreads();
    }
}

// ---------------------------------------------------------------------------
// k3: gather + index write + fused deterministic-enough loss (f64 atomics,
// last-block finalizes). 4 tokens per block.
__global__ __launch_bounds__(256)
void k3_gather_loss(const float4* __restrict__ x4, const float4* __restrict__ cb4,
                    const int* __restrict__ gidx, float4* __restrict__ out_tok,
                    float* __restrict__ out_idx, double* __restrict__ lsum,
                    int* __restrict__ lcount, float* __restrict__ out_loss,
                    int Ntok, double inv_total, int nblocks) {
    __shared__ float ps[4];
    int wv   = threadIdx.x >> 6;
    int lane = threadIdx.x & 63;
    int t    = (int)(blockIdx.x * 4 + wv);
    float s  = 0.f;
    if (t < Ntok) {
        int g = gidx[t];
        float4 cv = cb4[(size_t)g * D4 + lane];
        float4 xv = x4[(size_t)t * D4 + lane];
        out_tok[(size_t)t * D4 + lane] = cv;
        if (lane == 0) out_idx[t] = (float)g;
        float dx = cv.x - xv.x, dy = cv.y - xv.y, dz = cv.z - xv.z, dw = cv.w - xv.w;
        s = dx * dx + dy * dy + dz * dz + dw * dw;
        #pragma unroll
        for (int off = 32; off; off >>= 1) s += __shfl_xor(s, off, 64);
    }
    if (lane == 0) ps[wv] = s;
    __syncthreads();
    if (threadIdx.x == 0) {
        double p = (double)ps[0] + ps[1] + ps[2] + ps[3];
        atomicAdd(lsum, p);
        __threadfence();
        int done = atomicAdd(lcount, 1);
        if (done == nblocks - 1) {
            double tot = atomicAdd(lsum, 0.0);
            *out_loss = (float)(tot * inv_total);
        }
    }
}

// ---------------------------------------------------------------------------
// ---- f32 fallback path (round-2 proven) — only if ws too small ----
__global__ __launch_bounds__(256)
void k0_c2(const float4* __restrict__ cb4, const int* __restrict__ ridx,
           float* __restrict__ c2, int K, int kpad) {
    int k    = (int)(blockIdx.x * 4 + (threadIdx.x >> 6));
    int lane = threadIdx.x & 63;
    if (k >= kpad) return;
    double s = 0.0;
    if (k < K) {
        int row = ridx[k];
        float4 v = cb4[(size_t)row * D4 + lane];
        s = (double)v.x * v.x + (double)v.y * v.y
          + (double)v.z * v.z + (double)v.w * v.w;
    }
    #pragma unroll
    for (int off = 32; off; off >>= 1) s += __shfl_xor(s, off, 64);
    if (lane == 0) c2[k] = (k < K) ? (float)s : INFINITY;
}

__global__ __launch_bounds__(256, 2)
void fk1_argmin(const float4* __restrict__ x4, const float4* __restrict__ cb4,
                const int* __restrict__ ridx, const float* __restrict__ c2,
                float* __restrict__ pb1, float* __restrict__ pb2,
                int* __restrict__ pbi, int Ntok, int K, int kspan) {
    __shared__ float4 xs4[128 * 16];
    __shared__ float4 cs4[128 * 16];
    __shared__ float  c2_t[128];
    const int tid = threadIdx.x;
    const int r = tid >> 4, c = tid & 15;
    const int m0 = blockIdx.x * 128;
    const int kbase0 = blockIdx.y * kspan;
    float b1[8], b2[8]; int bi[8];
    #pragma unroll
    for (int i = 0; i < 8; ++i) { b1[i] = INFINITY; b2[i] = INFINITY; bi[i] = 0; }
    for (int t = 0; t < 8; ++t) {
        const int kbase = kbase0 + t * 128;
        if (kbase >= K) break;
        __syncthreads();
        if (tid < 128) c2_t[tid] = c2[kbase + tid];
        int cidx[8];
        #pragma unroll
        for (int q = 0; q < 8; ++q) {
            int k = kbase + 16 * q + r;
            cidx[q] = ridx[(k < K) ? k : 0];
        }
        float acc[8][8];
        #pragma unroll
        for (int i = 0; i < 8; ++i)
            #pragma unroll
            for (int j = 0; j < 8; ++j) acc[i][j] = 0.f;
        for (int ch = 0; ch < 4; ++ch) {
            __syncthreads();
            #pragma unroll
            for (int q = 0; q < 8; ++q) {
                int row = 16 * q + r;
                int p   = c ^ (row & 7);
                xs4[row * 16 + p] = x4[(size_t)(m0 + row) * D4 + ch * 16 + c];
                cs4[row * 16 + p] = cb4[(size_t)cidx[q] * D4 + ch * 16 + c];
            }
            __syncthreads();
            #pragma unroll 2
            for (int f = 0; f < 16; ++f) {
                float4 xf[8];
                #pragma unroll
                for (int i = 0; i < 8; ++i) xf[i] = xs4[(8 * r + i) * 16 + (f ^ i)];
                #pragma unroll
                for (int j = 0; j < 8; ++j) {
                    float4 cf = cs4[(c + 16 * j) * 16 + (f ^ (c & 7))];
                    #pragma unroll
                    for (int i = 0; i < 8; ++i) {
                        acc[i][j] = fmaf(xf[i].x, cf.x, acc[i][j]);
                        acc[i][j] = fmaf(xf[i].y, cf.y, acc[i][j]);
                        acc[i][j] = fmaf(xf[i].z, cf.z, acc[i][j]);
                        acc[i][j] = fmaf(xf[i].w, cf.w, acc[i][j]);
                    }
                }
            }
        }
        #pragma unroll
        for (int j = 0; j < 8; ++j) {
            float c2v = c2_t[c + 16 * j];
            int   k   = kbase + c + 16 * j;
            #pragma unroll
            for (int i = 0; i < 8; ++i) {
                float sc = fmaf(-2.f, acc[i][j], c2v);
                if (sc < b1[i]) { b2[i] = b1[i]; b1[i] = sc; bi[i] = k; }
                else            { b2[i] = fminf(b2[i], sc); }
            }
        }
    }
    __syncthreads();
    float* s1 = (float*)xs4;
    float* s2 = s1 + 128 * 16;
    int*   si = (int*)cs4;
    #pragma unroll
    for (int i = 0; i < 8; ++i) {
        int row = 8 * r + i;
        s1[row * 16 + c] = b1[i]; s2[row * 16 + c] = b2[i]; si[row * 16 + c] = bi[i];
    }
    __syncthreads();
    if (tid < 128) {
        float v1 = s1[tid * 16], v2 = s2[tid * 16];
        int   vi = si[tid * 16];
        #pragma unroll
        for (int cc = 1; cc < 16; ++cc) {
            float u1 = s1[tid * 16 + cc], u2 = s2[tid * 16 + cc];
            int   ui = si[tid * 16 + cc];
            if (u1 < v1 || (u1 == v1 && ui < vi)) { v2 = fminf(v1, u2); v1 = u1; vi = ui; }
            else                                  { v2 = fminf(v2, u1); }
        }
        size_t o = (size_t)blockIdx.y * Ntok + m0 + tid;
        pb1[o] = v1; pb2[o] = v2; pbi[o] = vi;
    }
}

// ---------------------------------------------------------------------------
extern "C" void kernel_launch(void* const* d_in, const int* in_sizes, int n_in,
                              void* d_out, int out_size, void* d_ws, size_t ws_size,
                              hipStream_t stream) {
    const float* x    = (const float*)d_in[0];
    const float* cb   = (const float*)d_in[1];
    const int*   ridx = (const int*)d_in[2];

    const int Ntok = in_sizes[0] / D;          // 16384
    const int K    = in_sizes[2];              // 3686

    float* out      = (float*)d_out;
    float* out_loss = out + (size_t)Ntok * D;
    float* out_idx  = out + (size_t)Ntok * D + 1;

    const float4* x4  = (const float4*)x;
    const float4* cb4 = (const float4*)cb;

    auto up = [](size_t v) { return (v + 255) & ~(size_t)255; };

    size_t need = 256 + up((size_t)KPAD * 512 * 2) + up((size_t)KPAD * 4)
                + 3 * up((size_t)NSPLIT * Ntok * 4) + 2 * up((size_t)Ntok * 4);

    const int gblocks = (Ntok + 3) / 4;
    const double inv_total = 1.0 / ((double)Ntok * (double)D);

    if (ws_size >= need) {
        // ---------------- MFMA pipeline path ----------------
        char* w = (char*)d_ws;
        double* lsum   = (double*)w;
        int*    cnt    = (int*)(w + 8);
        int*    lcount = (int*)(w + 12);  w += 256;
        ushort* cpack = (ushort*)w; w += up((size_t)KPAD * 512 * 2);
        float*  c2    = (float*)w;  w += up((size_t)KPAD * 4);
        float*  pb1   = (float*)w;  w += up((size_t)NSPLIT * Ntok * 4);
        float*  pb2   = (float*)w;  w += up((size_t)NSPLIT * Ntok * 4);
        int*    pbi   = (int*)w;    w += up((size_t)NSPLIT * Ntok * 4);
        int*    gidx  = (int*)w;    w += up((size_t)Ntok * 4);
        int*    tlist = (int*)w;

        ushort* xpack = (ushort*)d_out;   // exact fit in out_tok region

        hipMemsetAsync(d_ws, 0, 16, stream);
        p01_pack<<<dim3((Ntok + KPAD) / 4), dim3(256), 0, stream>>>(
            x4, cb4, ridx, xpack, cpack, c2, Ntok, K);
        k1_mfma<<<dim3((Ntok / TMTOK) * NSPLIT), dim3(256), 0, stream>>>(
            xpack, cpack, c2, pb1, pb2, pbi, Ntok);
        k2_combine<<<dim3((Ntok + 255) / 256), dim3(256), 0, stream>>>(
            pb1, pb2, pbi, ridx, gidx, tlist, cnt, Ntok, NSPLIT);
        k_recheck<<<dim3(256), dim3(256), 0, stream>>>(
            x4, cb4, ridx, tlist, cnt, gidx, K);
        k3_gather_loss<<<dim3(gblocks), dim3(256), 0, stream>>>(
            x4, cb4, gidx, (float4*)out, out_idx, lsum, lcount, out_loss,
            Ntok, inv_total, gblocks);
    } else {
        // ---------------- f32 fallback (round-2 proven) ----------------
        const int kpad  = 4096;
        const int kspan = 1024;
        char* w = (char*)d_ws;
        double* lsum   = (double*)w;
        int*    cnt    = (int*)(w + 8);
        int*    lcount = (int*)(w + 12);  w += 256;
        float* c2    = (float*)w;  w += up((size_t)kpad * 4);
        float* pb1   = (float*)w;  w += up((size_t)4 * Ntok * 4);
        float* pb2   = (float*)w;  w += up((size_t)4 * Ntok * 4);
        int*   pbi   = (int*)w;    w += up((size_t)4 * Ntok * 4);
        int*   gidx  = (int*)w;    w += up((size_t)Ntok * 4);
        int*   tlist = (int*)w;

        hipMemsetAsync(d_ws, 0, 16, stream);
        k0_c2<<<dim3(kpad / 4), dim3(256), 0, stream>>>(cb4, ridx, c2, K, kpad);
        fk1_argmin<<<dim3(Ntok / 128, 4), dim3(256), 0, stream>>>(
            x4, cb4, ridx, c2, pb1, pb2, pbi, Ntok, K, kspan);
        k2_combine<<<dim3((Ntok + 255) / 256), dim3(256), 0, stream>>>(
            pb1, pb2, pbi, ridx, gidx, tlist, cnt, Ntok, 4);
        k_recheck<<<dim3(256), dim3(256), 0, stream>>>(
            x4, cb4, ridx, tlist, cnt, gidx, K);
        k3_gather_loss<<<dim3(gblocks), dim3(256), 0, stream>>>(
            x4, cb4, gidx, (float4*)out, out_idx, lsum, lcount, out_loss,
            Ntok, inv_total, gblocks);
    }
}

// Round 5
// 639.579 us; speedup vs baseline: 1.1324x; 1.1324x over previous
//
#include <hip/hip_runtime.h>
#include <math.h>

// Problem geometry: D=256 fixed; N, K from in_sizes.
#define D      256
#define D4     64
#define TAU    6.0e-3f   // near-tie margin; bf16-3-slice score error ~2e-3

// ---- MFMA-path geometry ----
#define KPAD    4096     // padded subsampled-codebook size
#define NEB     128      // entry blocks of 32 (KPAD/32)
#define NSPLIT  4        // entry splits
#define KSPAN   1024     // entries per split
#define TNE     256      // entry tile
#define TMTOK   128      // token tile
#define KPK     768      // packed K'' = 3 slices of 256 (hh, hl, lh)
#define BK      32       // staged K'' chunk
#define NCHUNK  24       // chunks per tile (KPK/BK)
#define NTILE   4        // entry tiles per split (KSPAN/TNE)
#define NSTEP   96       // NTILE*NCHUNK
#define BUFU    12288    // ushorts per LDS buffer: A 16*512 + B 8*512 (24 KiB)

typedef short bf16x8 __attribute__((ext_vector_type(8)));
typedef float f32x16 __attribute__((ext_vector_type(16)));

#define GLD16(g, l) __builtin_amdgcn_global_load_lds( \
    (const __attribute__((address_space(1))) void*)(g), \
    (__attribute__((address_space(3))) void*)(l), 16, 0, 0)

__device__ inline ushort f2bf_rn(float f) {           // RNE f32 -> bf16 bits
    unsigned u = __float_as_uint(f);
    unsigned r = (u + 0x7fffu + ((u >> 16) & 1u)) >> 16;
    return (ushort)r;
}
__device__ inline float bf2f(ushort u) { return __uint_as_float(((unsigned)u) << 16); }
__device__ inline f32x16 zero16() {
    f32x16 z = {0,0,0,0,0,0,0,0,0,0,0,0,0,0,0,0};
    return z;
}
__device__ inline unsigned pack2(ushort a, ushort b) {
    return (unsigned)a | ((unsigned)b << 16);
}

// ---------------------------------------------------------------------------
// p01: fragment-major pack (pre-swizzled global so k1's global_load_lds is
// fully coalesced). Layouts:
//   xpF[kg][tb][512]: kg in [0,32) (0-15 = bf16hi k-groups, 16-31 = bf16lo),
//     tb = token-block of 32. Fragment elem: lane l -> token tb*32+(l&31),
//     k = (kg&15)*16 + (l>>5)*8 .. +8, 8 ushorts contiguous.
//   cpF[kg][eb][512]: same for codebook entries (zeros for pads).
// Plus c2[k] (f64-exact, +inf pads). One wave per fragment / per entry.
__global__ __launch_bounds__(256)
void p01_pack(const float4* __restrict__ x4, const float4* __restrict__ cb4,
              const int* __restrict__ ridx, ushort* __restrict__ xpF,
              ushort* __restrict__ cpF, float* __restrict__ c2,
              int Ntok, int K) {
    const int v    = (int)(blockIdx.x * 4 + (threadIdx.x >> 6));
    const int lane = threadIdx.x & 63;
    const int l31  = lane & 31, hi = lane >> 5;
    const int NTB  = Ntok >> 5;
    const int nx   = 32 * NTB;

    if (v < nx) {                                  // ---- x fragments ----
        int kg = v / NTB, tb = v - kg * NTB;
        int token = tb * 32 + l31;
        int f0 = (kg & 15) * 4 + hi * 2;           // float4 index
        float4 a = x4[(size_t)token * D4 + f0];
        float4 b = x4[(size_t)token * D4 + f0 + 1];
        float f[8] = {a.x, a.y, a.z, a.w, b.x, b.y, b.z, b.w};
        ushort u[8];
        if (kg < 16) {
            #pragma unroll
            for (int i = 0; i < 8; ++i) u[i] = f2bf_rn(f[i]);
        } else {
            #pragma unroll
            for (int i = 0; i < 8; ++i) {
                ushort hb = f2bf_rn(f[i]);
                u[i] = f2bf_rn(f[i] - bf2f(hb));
            }
        }
        uint4 o = {pack2(u[0],u[1]), pack2(u[2],u[3]),
                   pack2(u[4],u[5]), pack2(u[6],u[7])};
        *(uint4*)&xpF[((size_t)kg * NTB + tb) * 512 + lane * 8] = o;
        return;
    }
    int v2 = v - nx;
    if (v2 < 32 * NEB) {                           // ---- c fragments ----
        int kg = v2 >> 7, eb = v2 & (NEB - 1);
        int k = eb * 32 + l31;
        float f[8] = {0,0,0,0,0,0,0,0};
        if (k < K) {
            int row = ridx[k];
            int f0 = (kg & 15) * 4 + hi * 2;
            float4 a = cb4[(size_t)row * D4 + f0];
            float4 b = cb4[(size_t)row * D4 + f0 + 1];
            f[0]=a.x; f[1]=a.y; f[2]=a.z; f[3]=a.w;
            f[4]=b.x; f[5]=b.y; f[6]=b.z; f[7]=b.w;
        }
        ushort u[8];
        if (kg < 16) {
            #pragma unroll
            for (int i = 0; i < 8; ++i) u[i] = f2bf_rn(f[i]);
        } else {
            #pragma unroll
            for (int i = 0; i < 8; ++i) {
                ushort hb = f2bf_rn(f[i]);
                u[i] = f2bf_rn(f[i] - bf2f(hb));
            }
        }
        uint4 o = {pack2(u[0],u[1]), pack2(u[2],u[3]),
                   pack2(u[4],u[5]), pack2(u[6],u[7])};
        *(uint4*)&cpF[((size_t)kg * NEB + eb) * 512 + lane * 8] = o;
        return;
    }
    int k = v2 - 32 * NEB;                         // ---- c2 ----
    if (k >= KPAD) return;
    double s = 0.0;
    if (k < K) {
        int row = ridx[k];
        float4 vv = cb4[(size_t)row * D4 + lane];
        s = (double)vv.x * vv.x + (double)vv.y * vv.y
          + (double)vv.z * vv.z + (double)vv.w * vv.w;
    }
    #pragma unroll
    for (int off = 32; off; off >>= 1) s += __shfl_xor(s, off, 64);
    if (lane == 0) c2[k] = (k < K) ? (float)s : INFINITY;
}

// ---------------------------------------------------------------------------
// k1_mfma: 3-deep pipeline, fully-coalesced staging (1 GLD16 = 1 KB
// contiguous), counted vmcnt(12), 2 raw barriers/step, 16 MFMA/step/wave.
__global__ __launch_bounds__(256, 2)
void k1_mfma(const ushort* __restrict__ xpF, const ushort* __restrict__ cpF,
             const float* __restrict__ c2,
             float* __restrict__ pb1, float* __restrict__ pb2,
             int* __restrict__ pbi, int Ntok) {
    __shared__ __align__(16) ushort lds[3 * BUFU];   // 72 KiB
    __shared__ float c2all[NTILE * TNE];             // 4 KiB

    const int tid  = threadIdx.x;
    const int w    = tid >> 6;
    const int lane = tid & 63;
    const int we   = w >> 1;           // entry half (128 entries)
    const int wn   = w & 1;            // token half (64 tokens)
    const int hi   = lane >> 5;
    const int l31  = lane & 31;
    const int NTB  = Ntok >> 5;

    // XCD-bijective swizzle: 4 kb-siblings of one token tile share an XCD L2.
    int raw   = (int)blockIdx.x;
    int total = (int)gridDim.x;
    int swz   = ((total & 7) == 0) ? ((raw & 7) * (total >> 3) + (raw >> 3)) : raw;
    const int kb  = swz & (NSPLIT - 1);
    const int m0  = (swz >> 2) * TMTOK;
    const int tb0 = m0 >> 5;
    const int e0s = kb * KSPAN;
    const int eb0s = e0s >> 5;

    #pragma unroll
    for (int i = 0; i < 4; ++i) c2all[i * 256 + tid] = c2[e0s + i * 256 + tid];

    auto stage = [&](int tile, int chunk, int buf) {
        ushort* A = &lds[buf * BUFU];
        ushort* B = &lds[buf * BUFU + 8192];
        const int kg2 = chunk * 2;
        const int eb0 = eb0s + tile * 8;
        #pragma unroll
        for (int j = 0; j < 4; ++j) {                 // A: 16 frags / 4 waves
            int p = w * 4 + j, kc = p >> 3, g = p & 7;
            int kgp = kg2 + kc;                       // packed k16-group [0,48)
            int skg = (kgp < 32) ? kgp : kgp - 32;    // c: hi,lo,hi
            GLD16(cpF + ((size_t)skg * NEB + eb0 + g) * 512 + lane * 8,
                  &A[p * 512]);
        }
        #pragma unroll
        for (int j = 0; j < 2; ++j) {                 // B: 8 frags / 4 waves
            int q = w * 2 + j, kc = q >> 2, g = q & 3;
            int kgp = kg2 + kc;
            int skg = (kgp < 16) ? kgp : kgp - 16;    // x: hi,hi,lo
            GLD16(xpF + ((size_t)skg * NTB + tb0 + g) * 512 + lane * 8,
                  &B[q * 512]);
        }
    };

    float b1[2] = {INFINITY, INFINITY}, b2[2] = {INFINITY, INFINITY};
    int   bi[2] = {0, 0};
    f32x16 acc[4][2];
    #pragma unroll
    for (int mt = 0; mt < 4; ++mt)
        #pragma unroll
        for (int nt = 0; nt < 2; ++nt) acc[mt][nt] = zero16();

    // prefetch counters (division-free, clamped tail keeps vmcnt uniform)
    int tile_p = 0, chunk_p = 0;
    auto adv = [&]() {
        if (++chunk_p == NCHUNK) {
            chunk_p = 0;
            if (++tile_p == NTILE) { tile_p = NTILE - 1; chunk_p = NCHUNK - 1; }
        }
    };
    stage(tile_p, chunk_p, 0); adv();
    stage(tile_p, chunk_p, 1); adv();

    int bufr = 0, tile_c = 0, chunk_c = 0;
    for (int s = 0; s < NSTEP; ++s) {
        int bufc = bufr + 2; if (bufc >= 3) bufc -= 3;
        stage(tile_p, chunk_p, bufc); adv();

        asm volatile("s_waitcnt vmcnt(12)" ::: "memory");  // stage(s) landed
        __builtin_amdgcn_sched_barrier(0);
        __builtin_amdgcn_s_barrier();                      // buf[s] ready
        __builtin_amdgcn_sched_barrier(0);

        const ushort* A = &lds[bufr * BUFU];
        const ushort* B = &lds[bufr * BUFU + 8192];
        bf16x8 af[2][4], bfr[2][2];
        #pragma unroll
        for (int kc = 0; kc < 2; ++kc) {
            #pragma unroll
            for (int mt = 0; mt < 4; ++mt)
                af[kc][mt] = *(const bf16x8*)&A[(kc * 8 + we * 4 + mt) * 512 + lane * 8];
            #pragma unroll
            for (int nt = 0; nt < 2; ++nt)
                bfr[kc][nt] = *(const bf16x8*)&B[(kc * 4 + wn * 2 + nt) * 512 + lane * 8];
        }
        asm volatile("s_waitcnt lgkmcnt(0)" ::: "memory"); // frags in regs
        __builtin_amdgcn_sched_barrier(0);
        __builtin_amdgcn_s_barrier();                      // buf[s] reusable

        __builtin_amdgcn_s_setprio(1);
        #pragma unroll
        for (int kc = 0; kc < 2; ++kc)
            #pragma unroll
            for (int mt = 0; mt < 4; ++mt)
                #pragma unroll
                for (int nt = 0; nt < 2; ++nt)
                    acc[mt][nt] = __builtin_amdgcn_mfma_f32_32x32x16_bf16(
                        af[kc][mt], bfr[kc][nt], acc[mt][nt], 0, 0, 0);
        __builtin_amdgcn_s_setprio(0);

        if (chunk_c == NCHUNK - 1) {                       // per-tile epilogue
            #pragma unroll
            for (int nt = 0; nt < 2; ++nt)
                #pragma unroll
                for (int mt = 0; mt < 4; ++mt) {
                    #pragma unroll
                    for (int r = 0; r < 16; ++r) {
                        int rl = we * 128 + mt * 32 + (r & 3) + 8 * (r >> 2) + 4 * hi;
                        float sc = fmaf(-2.f, acc[mt][nt][r], c2all[tile_c * 256 + rl]);
                        int   k  = e0s + tile_c * 256 + rl;
                        bool better = (sc < b1[nt]) || (sc == b1[nt] && k < bi[nt]);
                        float nb2 = better ? b1[nt] : fminf(b2[nt], sc);
                        b1[nt] = better ? sc : b1[nt];
                        bi[nt] = better ? k  : bi[nt];
                        b2[nt] = nb2;
                    }
                    acc[mt][nt] = zero16();
                }
            chunk_c = 0; ++tile_c;
        } else ++chunk_c;
        bufr = bufr + 1; if (bufr >= 3) bufr = 0;
    }

    // merge lane <-> lane^32 (complementary rows, same token col)
    #pragma unroll
    for (int nt = 0; nt < 2; ++nt) {
        float o1 = __shfl_xor(b1[nt], 32, 64);
        float o2 = __shfl_xor(b2[nt], 32, 64);
        int   oi = __shfl_xor(bi[nt], 32, 64);
        if (o1 < b1[nt] || (o1 == b1[nt] && oi < bi[nt])) {
            b2[nt] = fminf(b1[nt], o2); b1[nt] = o1; bi[nt] = oi;
        } else b2[nt] = fminf(b2[nt], o1);
    }

    __syncthreads();                       // drains tail loads; LDS reusable
    float* s1 = (float*)lds;               // [we][128 tokens]
    float* s2 = s1 + 256;
    int*   si = (int*)(s2 + 256);
    if (hi == 0) {
        #pragma unroll
        for (int nt = 0; nt < 2; ++nt) {
            int tl = wn * 64 + nt * 32 + l31;
            s1[we * 128 + tl] = b1[nt];
            s2[we * 128 + tl] = b2[nt];
            si[we * 128 + tl] = bi[nt];
        }
    }
    __syncthreads();
    if (tid < TMTOK) {
        float v1 = s1[tid], v2 = s2[tid]; int vi = si[tid];
        float u1 = s1[128 + tid], u2 = s2[128 + tid]; int ui = si[128 + tid];
        if (u1 < v1 || (u1 == v1 && ui < vi)) { v2 = fminf(v1, u2); v1 = u1; vi = ui; }
        else                                  { v2 = fminf(v2, u1); }
        size_t o = (size_t)kb * Ntok + m0 + tid;
        pb1[o] = v1; pb2[o] = v2; pbi[o] = vi;
    }
}

// ---------------------------------------------------------------------------
// k2: combine splits per token; provisional global idx; flag near-ties.
__global__ __launch_bounds__(256)
void k2_combine(const float* __restrict__ pb1, const float* __restrict__ pb2,
                const int* __restrict__ pbi, const int* __restrict__ ridx,
                int* __restrict__ gidx, int* __restrict__ tlist,
                int* __restrict__ cnt, int Ntok, int nsplit) {
    int t = blockIdx.x * 256 + threadIdx.x;
    if (t >= Ntok) return;
    float v1 = INFINITY, v2 = INFINITY; int vi = 0x7fffffff;
    for (int kb = 0; kb < nsplit; ++kb) {
        size_t o = (size_t)kb * Ntok + t;
        float u1 = pb1[o], u2 = pb2[o]; int ui = pbi[o];
        if (u1 < v1 || (u1 == v1 && ui < vi)) { v2 = fminf(v1, u2); v1 = u1; vi = ui; }
        else                                  { v2 = fminf(v2, u1); }
    }
    gidx[t] = ridx[vi];
    if (v2 - v1 < TAU) {
        int pos = atomicAdd(cnt, 1);
        tlist[pos] = t;
    }
}

// ---------------------------------------------------------------------------
// k_recheck: exact f64 argmin, lexicographic tie-break, flagged tokens only.
__global__ __launch_bounds__(256)
void k_recheck(const float4* __restrict__ x4, const float4* __restrict__ cb4,
               const int* __restrict__ ridx, const int* __restrict__ tlist,
               const int* __restrict__ cnt, int* __restrict__ gidx, int K) {
    __shared__ float4 xls[D4];
    __shared__ double rv[256];
    __shared__ int    rix[256];
    const int tid = threadIdx.x;
    const int n   = *cnt;
    for (int fi = blockIdx.x; fi < n; fi += gridDim.x) {
        int t = tlist[fi];
        if (tid < D4) xls[tid] = x4[(size_t)t * D4 + tid];
        __syncthreads();
        double bv = INFINITY; int bi = 0x7fffffff;
        for (int k = tid; k < K; k += 256) {
            const float4* cr = cb4 + (size_t)ridx[k] * D4;
            double s = 0.0, cc = 0.0;
            #pragma unroll 4
            for (int d = 0; d < D4; ++d) {
                float4 cv = cr[d], xv = xls[d];
                s  = fma((double)cv.x, (double)xv.x, s);
                s  = fma((double)cv.y, (double)xv.y, s);
                s  = fma((double)cv.z, (double)xv.z, s);
                s  = fma((double)cv.w, (double)xv.w, s);
                cc = fma((double)cv.x, (double)cv.x, cc);
                cc = fma((double)cv.y, (double)cv.y, cc);
                cc = fma((double)cv.z, (double)cv.z, cc);
                cc = fma((double)cv.w, (double)cv.w, cc);
            }
            double sc = cc - 2.0 * s;
            if (sc < bv || (sc == bv && k < bi)) { bv = sc; bi = k; }
        }
        rv[tid] = bv; rix[tid] = bi;
        __syncthreads();
        for (int st = 128; st; st >>= 1) {
            if (tid < st) {
                double u = rv[tid + st]; int ui = rix[tid + st];
                if (u < rv[tid] || (u == rv[tid] && ui < rix[tid])) {
                    rv[tid] = u; rix[tid] = ui;
                }
            }
            __syncthreads();
        }
        if (tid == 0) gidx[t] = ridx[rix[0]];
        __syncthreads();
    }
}

// ---------------------------------------------------------------------------
// k3: gather + index write + fused loss (f64 atomics, last block finalizes).
__global__ __launch_bounds__(256)
void k3_gather_loss(const float4* __restrict__ x4, const float4* __restrict__ cb4,
                    const int* __restrict__ gidx, float4* __restrict__ out_tok,
                    float* __restrict__ out_idx, double* __restrict__ lsum,
                    int* __restrict__ lcount, float* __restrict__ out_loss,
                    int Ntok, double inv_total, int nblocks) {
    __shared__ float ps[4];
    int wv   = threadIdx.x >> 6;
    int lane = threadIdx.x & 63;
    int t    = (int)(blockIdx.x * 4 + wv);
    float s  = 0.f;
    if (t < Ntok) {
        int g = gidx[t];
        float4 cv = cb4[(size_t)g * D4 + lane];
        float4 xv = x4[(size_t)t * D4 + lane];
        out_tok[(size_t)t * D4 + lane] = cv;
        if (lane == 0) out_idx[t] = (float)g;
        float dx = cv.x - xv.x, dy = cv.y - xv.y, dz = cv.z - xv.z, dw = cv.w - xv.w;
        s = dx * dx + dy * dy + dz * dz + dw * dw;
        #pragma unroll
        for (int off = 32; off; off >>= 1) s += __shfl_xor(s, off, 64);
    }
    if (lane == 0) ps[wv] = s;
    __syncthreads();
    if (threadIdx.x == 0) {
        double p = (double)ps[0] + ps[1] + ps[2] + ps[3];
        atomicAdd(lsum, p);
        __threadfence();
        int done = atomicAdd(lcount, 1);
        if (done == nblocks - 1) {
            double tot = atomicAdd(lsum, 0.0);
            *out_loss = (float)(tot * inv_total);
        }
    }
}

// ---------------------------------------------------------------------------
// ---- f32 fallback path (round-2 proven) — only if ws too small ----
__global__ __launch_bounds__(256)
void k0_c2(const float4* __restrict__ cb4, const int* __restrict__ ridx,
           float* __restrict__ c2, int K, int kpad) {
    int k    = (int)(blockIdx.x * 4 + (threadIdx.x >> 6));
    int lane = threadIdx.x & 63;
    if (k >= kpad) return;
    double s = 0.0;
    if (k < K) {
        int row = ridx[k];
        float4 v = cb4[(size_t)row * D4 + lane];
        s = (double)v.x * v.x + (double)v.y * v.y
          + (double)v.z * v.z + (double)v.w * v.w;
    }
    #pragma unroll
    for (int off = 32; off; off >>= 1) s += __shfl_xor(s, off, 64);
    if (lane == 0) c2[k] = (k < K) ? (float)s : INFINITY;
}

__global__ __launch_bounds__(256, 2)
void fk1_argmin(const float4* __restrict__ x4, const float4* __restrict__ cb4,
                const int* __restrict__ ridx, const float* __restrict__ c2,
                float* __restrict__ pb1, float* __restrict__ pb2,
                int* __restrict__ pbi, int Ntok, int K, int kspan) {
    __shared__ float4 xs4[128 * 16];
    __shared__ float4 cs4[128 * 16];
    __shared__ float  c2_t[128];
    const int tid = threadIdx.x;
    const int r = tid >> 4, c = tid & 15;
    const int m0 = blockIdx.x * 128;
    const int kbase0 = blockIdx.y * kspan;
    float b1[8], b2[8]; int bi[8];
    #pragma unroll
    for (int i = 0; i < 8; ++i) { b1[i] = INFINITY; b2[i] = INFINITY; bi[i] = 0; }
    for (int t = 0; t < 8; ++t) {
        const int kbase = kbase0 + t * 128;
        if (kbase >= K) break;
        __syncthreads();
        if (tid < 128) c2_t[tid] = c2[kbase + tid];
        int cidx[8];
        #pragma unroll
        for (int q = 0; q < 8; ++q) {
            int k = kbase + 16 * q + r;
            cidx[q] = ridx[(k < K) ? k : 0];
        }
        float acc[8][8];
        #pragma unroll
        for (int i = 0; i < 8; ++i)
            #pragma unroll
            for (int j = 0; j < 8; ++j) acc[i][j] = 0.f;
        for (int ch = 0; ch < 4; ++ch) {
            __syncthreads();
            #pragma unroll
            for (int q = 0; q < 8; ++q) {
                int row = 16 * q + r;
                int p   = c ^ (row & 7);
                xs4[row * 16 + p] = x4[(size_t)(m0 + row) * D4 + ch * 16 + c];
                cs4[row * 16 + p] = cb4[(size_t)cidx[q] * D4 + ch * 16 + c];
            }
            __syncthreads();
            #pragma unroll 2
            for (int f = 0; f < 16; ++f) {
                float4 xf[8];
                #pragma unroll
                for (int i = 0; i < 8; ++i) xf[i] = xs4[(8 * r + i) * 16 + (f ^ i)];
                #pragma unroll
                for (int j = 0; j < 8; ++j) {
                    float4 cf = cs4[(c + 16 * j) * 16 + (f ^ (c & 7))];
                    #pragma unroll
                    for (int i = 0; i < 8; ++i) {
                        acc[i][j] = fmaf(xf[i].x, cf.x, acc[i][j]);
                        acc[i][j] = fmaf(xf[i].y, cf.y, acc[i][j]);
                        acc[i][j] = fmaf(xf[i].z, cf.z, acc[i][j]);
                        acc[i][j] = fmaf(xf[i].w, cf.w, acc[i][j]);
                    }
                }
            }
        }
        #pragma unroll
        for (int j = 0; j < 8; ++j) {
            float c2v = c2_t[c + 16 * j];
            int   k   = kbase + c + 16 * j;
            #pragma unroll
            for (int i = 0; i < 8; ++i) {
                float sc = fmaf(-2.f, acc[i][j], c2v);
                if (sc < b1[i]) { b2[i] = b1[i]; b1[i] = sc; bi[i] = k; }
                else            { b2[i] = fminf(b2[i], sc); }
            }
        }
    }
    __syncthreads();
    float* s1 = (float*)xs4;
    float* s2 = s1 + 128 * 16;
    int*   si = (int*)cs4;
    #pragma unroll
    for (int i = 0; i < 8; ++i) {
        int row = 8 * r + i;
        s1[row * 16 + c] = b1[i]; s2[row * 16 + c] = b2[i]; si[row * 16 + c] = bi[i];
    }
    __syncthreads();
    if (tid < 128) {
        float v1 = s1[tid * 16], v2 = s2[tid * 16];
        int   vi = si[tid * 16];
        #pragma unroll
        for (int cc = 1; cc < 16; ++cc) {
            float u1 = s1[tid * 16 + cc], u2 = s2[tid * 16 + cc];
            int   ui = si[tid * 16 + cc];
            if (u1 < v1 || (u1 == v1 && ui < vi)) { v2 = fminf(v1, u2); v1 = u1; vi = ui; }
            else                                  { v2 = fminf(v2, u1); }
        }
        size_t o = (size_t)blockIdx.y * Ntok + m0 + tid;
        pb1[o] = v1; pb2[o] = v2; pbi[o] = vi;
    }
}

// ---------------------------------------------------------------------------
extern "C" void kernel_launch(void* const* d_in, const int* in_sizes, int n_in,
                              void* d_out, int out_size, void* d_ws, size_t ws_size,
                              hipStream_t stream) {
    const float* x    = (const float*)d_in[0];
    const float* cb   = (const float*)d_in[1];
    const int*   ridx = (const int*)d_in[2];

    const int Ntok = in_sizes[0] / D;          // 16384
    const int K    = in_sizes[2];              // 3686

    float* out      = (float*)d_out;
    float* out_loss = out + (size_t)Ntok * D;
    float* out_idx  = out + (size_t)Ntok * D + 1;

    const float4* x4  = (const float4*)x;
    const float4* cb4 = (const float4*)cb;

    auto up = [](size_t v) { return (v + 255) & ~(size_t)255; };

    size_t need = 256 + up((size_t)KPAD * 512 * 2) + up((size_t)KPAD * 4)
                + 3 * up((size_t)NSPLIT * Ntok * 4) + 2 * up((size_t)Ntok * 4);

    const int gblocks = (Ntok + 3) / 4;
    const double inv_total = 1.0 / ((double)Ntok * (double)D);

    if (ws_size >= need && (Ntok & 127) == 0) {
        // ---------------- MFMA pipeline path ----------------
        char* w = (char*)d_ws;
        double* lsum   = (double*)w;
        int*    cnt    = (int*)(w + 8);
        int*    lcount = (int*)(w + 12);  w += 256;
        ushort* cpF   = (ushort*)w; w += up((size_t)KPAD * 512 * 2);
        float*  c2    = (float*)w;  w += up((size_t)KPAD * 4);
        float*  pb1   = (float*)w;  w += up((size_t)NSPLIT * Ntok * 4);
        float*  pb2   = (float*)w;  w += up((size_t)NSPLIT * Ntok * 4);
        int*    pbi   = (int*)w;    w += up((size_t)NSPLIT * Ntok * 4);
        int*    gidx  = (int*)w;    w += up((size_t)Ntok * 4);
        int*    tlist = (int*)w;

        ushort* xpF = (ushort*)d_out;   // 16.8 MB: exact fit in out_tok region

        const int nwav = 32 * (Ntok >> 5) + 32 * NEB + KPAD;

        hipMemsetAsync(d_ws, 0, 16, stream);
        p01_pack<<<dim3((nwav + 3) / 4), dim3(256), 0, stream>>>(
            x4, cb4, ridx, xpF, cpF, c2, Ntok, K);
        k1_mfma<<<dim3((Ntok / TMTOK) * NSPLIT), dim3(256), 0, stream>>>(
            xpF, cpF, c2, pb1, pb2, pbi, Ntok);
        k2_combine<<<dim3((Ntok + 255) / 256), dim3(256), 0, stream>>>(
            pb1, pb2, pbi, ridx, gidx, tlist, cnt, Ntok, NSPLIT);
        k_recheck<<<dim3(128), dim3(256), 0, stream>>>(
            x4, cb4, ridx, tlist, cnt, gidx, K);
        k3_gather_loss<<<dim3(gblocks), dim3(256), 0, stream>>>(
            x4, cb4, gidx, (float4*)out, out_idx, lsum, lcount, out_loss,
            Ntok, inv_total, gblocks);
    } else {
        // ---------------- f32 fallback (round-2 proven) ----------------
        const int kpad  = 4096;
        const int kspan = 1024;
        char* w = (char*)d_ws;
        double* lsum   = (double*)w;
        int*    cnt    = (int*)(w + 8);
        int*    lcount = (int*)(w + 12);  w += 256;
        float* c2    = (float*)w;  w += up((size_t)kpad * 4);
        float* pb1   = (float*)w;  w += up((size_t)4 * Ntok * 4);
        float* pb2   = (float*)w;  w += up((size_t)4 * Ntok * 4);
        int*   pbi   = (int*)w;    w += up((size_t)4 * Ntok * 4);
        int*   gidx  = (int*)w;    w += up((size_t)Ntok * 4);
        int*   tlist = (int*)w;

        hipMemsetAsync(d_ws, 0, 16, stream);
        k0_c2<<<dim3(kpad / 4), dim3(256), 0, stream>>>(cb4, ridx, c2, K, kpad);
        fk1_argmin<<<dim3(Ntok / 128, 4), dim3(256), 0, stream>>>(
            x4, cb4, ridx, c2, pb1, pb2, pbi, Ntok, K, kspan);
        k2_combine<<<dim3((Ntok + 255) / 256), dim3(256), 0, stream>>>(
            pb1, pb2, pbi, ridx, gidx, tlist, cnt, Ntok, 4);
        k_recheck<<<dim3(128), dim3(256), 0, stream>>>(
            x4, cb4, ridx, tlist, cnt, gidx, K);
        k3_gather_loss<<<dim3(gblocks), dim3(256), 0, stream>>>(
            x4, cb4, gidx, (float4*)out, out_idx, lsum, lcount, out_loss,
            Ntok, inv_total, gblocks);
    }
}

// Round 6
// 589.148 us; speedup vs baseline: 1.2293x; 1.0856x over previous
//
#include <hip/hip_runtime.h>
#include <math.h>

// Problem geometry: D=256 fixed; N, K from in_sizes.
#define D      256
#define D4     64
#define TAU    6.0e-3f   // near-tie margin; bf16-3-product score error ~2e-3

// ---- MFMA-path geometry (round 6) ----
#define KPAD    4096     // padded subsampled-codebook size
#define NEB     128      // entry blocks of 32 (KPAD/32)
#define NSPLIT  8        // entry splits; kb = blockIdx.x & 7 -> XCD-pinned
#define KSPAN   512      // entries per block (one tile, no re-reads)
#define TMTOK   128      // tokens per block
#define NSTEPK  16       // k16-groups (D/16)
#define AFRAGS  32       // per step: 16 eb x {hi,lo}
#define BFRAGS  8        // per step: 4 tb x {hi,lo}
#define BUFU    ((AFRAGS + BFRAGS) * 512)   // ushorts per LDS buffer (40 KiB)

typedef short bf16x8 __attribute__((ext_vector_type(8)));
typedef float f32x16 __attribute__((ext_vector_type(16)));

#define GLD16(g, l) __builtin_amdgcn_global_load_lds( \
    (const __attribute__((address_space(1))) void*)(g), \
    (__attribute__((address_space(3))) void*)(l), 16, 0, 0)

__device__ inline ushort f2bf_rn(float f) {           // RNE f32 -> bf16 bits
    unsigned u = __float_as_uint(f);
    unsigned r = (u + 0x7fffu + ((u >> 16) & 1u)) >> 16;
    return (ushort)r;
}
__device__ inline float bf2f(ushort u) { return __uint_as_float(((unsigned)u) << 16); }
__device__ inline f32x16 zero16() {
    f32x16 z = {0,0,0,0,0,0,0,0,0,0,0,0,0,0,0,0};
    return z;
}
__device__ inline unsigned pack2(ushort a, ushort b) {
    return (unsigned)a | ((unsigned)b << 16);
}

// ---------------------------------------------------------------------------
// p01: fragment-major pack. xpF[kg][tb][512], cpF[kg][eb][512]:
// kg in [0,32): kg<16 = bf16hi of k16-group kg, kg>=16 = bf16lo of kg-16.
// Fragment: lane l -> row blk*32+(l&31), k'' = (l>>5)*8..+8 contiguous.
// Plus c2[k] (f64-exact, +inf pads). One wave per fragment / entry.
__global__ __launch_bounds__(256)
void p01_pack(const float4* __restrict__ x4, const float4* __restrict__ cb4,
              const int* __restrict__ ridx, ushort* __restrict__ xpF,
              ushort* __restrict__ cpF, float* __restrict__ c2,
              int Ntok, int K) {
    const int v    = (int)(blockIdx.x * 4 + (threadIdx.x >> 6));
    const int lane = threadIdx.x & 63;
    const int l31  = lane & 31, hi = lane >> 5;
    const int NTB  = Ntok >> 5;
    const int nx   = 32 * NTB;

    if (v < nx) {                                  // ---- x fragments ----
        int kg = v / NTB, tb = v - kg * NTB;
        int token = tb * 32 + l31;
        int f0 = (kg & 15) * 4 + hi * 2;           // float4 index
        float4 a = x4[(size_t)token * D4 + f0];
        float4 b = x4[(size_t)token * D4 + f0 + 1];
        float f[8] = {a.x, a.y, a.z, a.w, b.x, b.y, b.z, b.w};
        ushort u[8];
        if (kg < 16) {
            #pragma unroll
            for (int i = 0; i < 8; ++i) u[i] = f2bf_rn(f[i]);
        } else {
            #pragma unroll
            for (int i = 0; i < 8; ++i) {
                ushort hb = f2bf_rn(f[i]);
                u[i] = f2bf_rn(f[i] - bf2f(hb));
            }
        }
        uint4 o = {pack2(u[0],u[1]), pack2(u[2],u[3]),
                   pack2(u[4],u[5]), pack2(u[6],u[7])};
        *(uint4*)&xpF[((size_t)kg * NTB + tb) * 512 + lane * 8] = o;
        return;
    }
    int v2 = v - nx;
    if (v2 < 32 * NEB) {                           // ---- c fragments ----
        int kg = v2 >> 7, eb = v2 & (NEB - 1);
        int k = eb * 32 + l31;
        float f[8] = {0,0,0,0,0,0,0,0};
        if (k < K) {
            int row = ridx[k];
            int f0 = (kg & 15) * 4 + hi * 2;
            float4 a = cb4[(size_t)row * D4 + f0];
            float4 b = cb4[(size_t)row * D4 + f0 + 1];
            f[0]=a.x; f[1]=a.y; f[2]=a.z; f[3]=a.w;
            f[4]=b.x; f[5]=b.y; f[6]=b.z; f[7]=b.w;
        }
        ushort u[8];
        if (kg < 16) {
            #pragma unroll
            for (int i = 0; i < 8; ++i) u[i] = f2bf_rn(f[i]);
        } else {
            #pragma unroll
            for (int i = 0; i < 8; ++i) {
                ushort hb = f2bf_rn(f[i]);
                u[i] = f2bf_rn(f[i] - bf2f(hb));
            }
        }
        uint4 o = {pack2(u[0],u[1]), pack2(u[2],u[3]),
                   pack2(u[4],u[5]), pack2(u[6],u[7])};
        *(uint4*)&cpF[((size_t)kg * NEB + eb) * 512 + lane * 8] = o;
        return;
    }
    int k = v2 - 32 * NEB;                         // ---- c2 ----
    if (k >= KPAD) return;
    double s = 0.0;
    if (k < K) {
        int row = ridx[k];
        float4 vv = cb4[(size_t)row * D4 + lane];
        s = (double)vv.x * vv.x + (double)vv.y * vv.y
          + (double)vv.z * vv.z + (double)vv.w * vv.w;
    }
    #pragma unroll
    for (int off = 32; off; off >>= 1) s += __shfl_xor(s, off, 64);
    if (lane == 0) c2[k] = (k < K) ? (float)s : INFINITY;
}

// ---------------------------------------------------------------------------
// k1_mfma v3: 512 threads (8 waves), 512 entries x 128 tokens per block.
// Per step (one k16-group): stage {c_hi,c_lo,x_hi,x_lo} frags (40 KB), then
// 3 products per acc tile from 4 unique frags (hh, lo_c*hi_x, hi_c*lo_x).
// 3-buffer counted-vmcnt pipeline; XCD-pinned entry split (kb = blk & 7).
__global__ __launch_bounds__(512, 2)
void k1_mfma(const ushort* __restrict__ xpF, const ushort* __restrict__ cpF,
             const float* __restrict__ c2,
             float* __restrict__ pb1, float* __restrict__ pb2,
             int* __restrict__ pbi, int Ntok) {
    __shared__ __align__(16) ushort lds[3 * BUFU];   // 120 KiB
    __shared__ float c2all[KSPAN];                   // 2 KiB

    const int tid  = threadIdx.x;
    const int w    = tid >> 6;         // 0..7
    const int lane = tid & 63;
    const int we   = w >> 1;           // 0..3: entry quarter (128 entries)
    const int wn   = w & 1;            // 0..1: token half (64 tokens)
    const int hi   = lane >> 5;
    const int l31  = lane & 31;
    const int NTB  = Ntok >> 5;

    const int raw = (int)blockIdx.x;
    const int kb  = raw & (NSPLIT - 1);        // XCD-pinned split
    const int m0  = (raw >> 3) * TMTOK;
    const int tb0 = m0 >> 5;
    const int e0s = kb * KSPAN;
    const int eb0 = e0s >> 5;

    c2all[tid] = c2[e0s + tid];                // tid < 512 == KSPAN

    auto stage = [&](int g, int buf) {
        ushort* A = &lds[buf * BUFU];
        ushort* B = A + AFRAGS * 512;
        #pragma unroll
        for (int j = 0; j < 4; ++j) {          // A: 32 frags / 8 waves
            int idx = w * 4 + j;
            int hl = idx >> 4, ebl = idx & 15;
            GLD16(cpF + ((size_t)(g + hl * 16) * NEB + eb0 + ebl) * 512 + lane * 8,
                  &A[idx * 512]);
        }
        {                                       // B: 8 frags / 8 waves
            int hl = w >> 2, tbl = w & 3;
            GLD16(xpF + ((size_t)(g + hl * 16) * NTB + tb0 + tbl) * 512 + lane * 8,
                  &B[w * 512]);
        }
    };

    f32x16 acc[4][2];
    #pragma unroll
    for (int et = 0; et < 4; ++et)
        #pragma unroll
        for (int tt = 0; tt < 2; ++tt) acc[et][tt] = zero16();

    stage(0, 0);
    stage(1, 1);

    int bufr = 0;
    for (int s = 0; s < NSTEPK; ++s) {
        int sp = s + 2; if (sp > NSTEPK - 1) sp = NSTEPK - 1;  // uniform counts
        int bufc = bufr + 2; if (bufc >= 3) bufc -= 3;
        stage(sp, bufc);

        asm volatile("s_waitcnt vmcnt(10)" ::: "memory");  // stage(s) landed
        __builtin_amdgcn_sched_barrier(0);
        __builtin_amdgcn_s_barrier();                      // buf[s] ready
        __builtin_amdgcn_sched_barrier(0);

        const ushort* A = &lds[bufr * BUFU];
        const ushort* B = A + AFRAGS * 512;
        bf16x8 ah[4], al[4], bh[2], bl[2];
        #pragma unroll
        for (int et = 0; et < 4; ++et) {
            ah[et] = *(const bf16x8*)&A[(we * 4 + et) * 512 + lane * 8];
            al[et] = *(const bf16x8*)&A[(16 + we * 4 + et) * 512 + lane * 8];
        }
        #pragma unroll
        for (int tt = 0; tt < 2; ++tt) {
            bh[tt] = *(const bf16x8*)&B[(wn * 2 + tt) * 512 + lane * 8];
            bl[tt] = *(const bf16x8*)&B[(4 + wn * 2 + tt) * 512 + lane * 8];
        }
        asm volatile("s_waitcnt lgkmcnt(0)" ::: "memory"); // frags in regs
        __builtin_amdgcn_sched_barrier(0);
        __builtin_amdgcn_s_barrier();                      // buf[s] reusable

        __builtin_amdgcn_s_setprio(1);
        #pragma unroll
        for (int et = 0; et < 4; ++et)
            #pragma unroll
            for (int tt = 0; tt < 2; ++tt) {
                acc[et][tt] = __builtin_amdgcn_mfma_f32_32x32x16_bf16(
                    ah[et], bh[tt], acc[et][tt], 0, 0, 0);
                acc[et][tt] = __builtin_amdgcn_mfma_f32_32x32x16_bf16(
                    al[et], bh[tt], acc[et][tt], 0, 0, 0);
                acc[et][tt] = __builtin_amdgcn_mfma_f32_32x32x16_bf16(
                    ah[et], bl[tt], acc[et][tt], 0, 0, 0);
            }
        __builtin_amdgcn_s_setprio(0);

        bufr = bufr + 1; if (bufr >= 3) bufr = 0;
    }

    // epilogue: scores + branchless top-2 (lexicographic tie-break)
    float b1[2] = {INFINITY, INFINITY}, b2[2] = {INFINITY, INFINITY};
    int   bi[2] = {0, 0};
    #pragma unroll
    for (int tt = 0; tt < 2; ++tt)
        #pragma unroll
        for (int et = 0; et < 4; ++et)
            #pragma unroll
            for (int r = 0; r < 16; ++r) {
                int rl = we * 128 + et * 32 + (r & 3) + 8 * (r >> 2) + 4 * hi;
                float sc = fmaf(-2.f, acc[et][tt][r], c2all[rl]);
                int   k  = e0s + rl;
                bool better = (sc < b1[tt]) || (sc == b1[tt] && k < bi[tt]);
                float nb2 = better ? b1[tt] : fminf(b2[tt], sc);
                b1[tt] = better ? sc : b1[tt];
                bi[tt] = better ? k  : bi[tt];
                b2[tt] = nb2;
            }

    // merge lane <-> lane^32 (complementary rows, same token col)
    #pragma unroll
    for (int tt = 0; tt < 2; ++tt) {
        float o1 = __shfl_xor(b1[tt], 32, 64);
        float o2 = __shfl_xor(b2[tt], 32, 64);
        int   oi = __shfl_xor(bi[tt], 32, 64);
        if (o1 < b1[tt] || (o1 == b1[tt] && oi < bi[tt])) {
            b2[tt] = fminf(b1[tt], o2); b1[tt] = o1; bi[tt] = oi;
        } else b2[tt] = fminf(b2[tt], o1);
    }

    __syncthreads();                       // drains tail loads; LDS reusable
    float* s1 = (float*)lds;               // [we 0..3][128 tokens]
    float* s2 = s1 + 512;
    int*   si = (int*)(s2 + 512);
    if (hi == 0) {
        #pragma unroll
        for (int tt = 0; tt < 2; ++tt) {
            int tl = wn * 64 + tt * 32 + l31;
            s1[we * 128 + tl] = b1[tt];
            s2[we * 128 + tl] = b2[tt];
            si[we * 128 + tl] = bi[tt];
        }
    }
    __syncthreads();
    if (tid < TMTOK) {
        float v1 = s1[tid], v2 = s2[tid]; int vi = si[tid];
        #pragma unroll
        for (int g = 1; g < 4; ++g) {
            float u1 = s1[g * 128 + tid], u2 = s2[g * 128 + tid];
            int   ui = si[g * 128 + tid];
            if (u1 < v1 || (u1 == v1 && ui < vi)) { v2 = fminf(v1, u2); v1 = u1; vi = ui; }
            else                                  { v2 = fminf(v2, u1); }
        }
        size_t o = (size_t)kb * Ntok + m0 + tid;
        pb1[o] = v1; pb2[o] = v2; pbi[o] = vi;
    }
}

// ---------------------------------------------------------------------------
// k2: combine splits per token; provisional global idx; flag near-ties.
__global__ __launch_bounds__(256)
void k2_combine(const float* __restrict__ pb1, const float* __restrict__ pb2,
                const int* __restrict__ pbi, const int* __restrict__ ridx,
                int* __restrict__ gidx, int* __restrict__ tlist,
                int* __restrict__ cnt, int Ntok, int nsplit) {
    int t = blockIdx.x * 256 + threadIdx.x;
    if (t >= Ntok) return;
    float v1 = INFINITY, v2 = INFINITY; int vi = 0x7fffffff;
    for (int kb = 0; kb < nsplit; ++kb) {
        size_t o = (size_t)kb * Ntok + t;
        float u1 = pb1[o], u2 = pb2[o]; int ui = pbi[o];
        if (u1 < v1 || (u1 == v1 && ui < vi)) { v2 = fminf(v1, u2); v1 = u1; vi = ui; }
        else                                  { v2 = fminf(v2, u1); }
    }
    gidx[t] = ridx[vi];
    if (v2 - v1 < TAU) {
        int pos = atomicAdd(cnt, 1);
        tlist[pos] = t;
    }
}

// ---------------------------------------------------------------------------
// k_recheck: exact f64 argmin, lexicographic tie-break, flagged tokens only.
__global__ __launch_bounds__(256)
void k_recheck(const float4* __restrict__ x4, const float4* __restrict__ cb4,
               const int* __restrict__ ridx, const int* __restrict__ tlist,
               const int* __restrict__ cnt, int* __restrict__ gidx, int K) {
    __shared__ float4 xls[D4];
    __shared__ double rv[256];
    __shared__ int    rix[256];
    const int tid = threadIdx.x;
    const int n   = *cnt;
    for (int fi = blockIdx.x; fi < n; fi += gridDim.x) {
        int t = tlist[fi];
        if (tid < D4) xls[tid] = x4[(size_t)t * D4 + tid];
        __syncthreads();
        double bv = INFINITY; int bi = 0x7fffffff;
        for (int k = tid; k < K; k += 256) {
            const float4* cr = cb4 + (size_t)ridx[k] * D4;
            double s = 0.0, cc = 0.0;
            #pragma unroll 4
            for (int d = 0; d < D4; ++d) {
                float4 cv = cr[d], xv = xls[d];
                s  = fma((double)cv.x, (double)xv.x, s);
                s  = fma((double)cv.y, (double)xv.y, s);
                s  = fma((double)cv.z, (double)xv.z, s);
                s  = fma((double)cv.w, (double)xv.w, s);
                cc = fma((double)cv.x, (double)cv.x, cc);
                cc = fma((double)cv.y, (double)cv.y, cc);
                cc = fma((double)cv.z, (double)cv.z, cc);
                cc = fma((double)cv.w, (double)cv.w, cc);
            }
            double sc = cc - 2.0 * s;
            if (sc < bv || (sc == bv && k < bi)) { bv = sc; bi = k; }
        }
        rv[tid] = bv; rix[tid] = bi;
        __syncthreads();
        for (int st = 128; st; st >>= 1) {
            if (tid < st) {
                double u = rv[tid + st]; int ui = rix[tid + st];
                if (u < rv[tid] || (u == rv[tid] && ui < rix[tid])) {
                    rv[tid] = u; rix[tid] = ui;
                }
            }
            __syncthreads();
        }
        if (tid == 0) gidx[t] = ridx[rix[0]];
        __syncthreads();
    }
}

// ---------------------------------------------------------------------------
// k3: gather + index write + fused loss (f64 atomics, last block finalizes).
__global__ __launch_bounds__(256)
void k3_gather_loss(const float4* __restrict__ x4, const float4* __restrict__ cb4,
                    const int* __restrict__ gidx, float4* __restrict__ out_tok,
                    float* __restrict__ out_idx, double* __restrict__ lsum,
                    int* __restrict__ lcount, float* __restrict__ out_loss,
                    int Ntok, double inv_total, int nblocks) {
    __shared__ float ps[4];
    int wv   = threadIdx.x >> 6;
    int lane = threadIdx.x & 63;
    int t    = (int)(blockIdx.x * 4 + wv);
    float s  = 0.f;
    if (t < Ntok) {
        int g = gidx[t];
        float4 cv = cb4[(size_t)g * D4 + lane];
        float4 xv = x4[(size_t)t * D4 + lane];
        out_tok[(size_t)t * D4 + lane] = cv;
        if (lane == 0) out_idx[t] = (float)g;
        float dx = cv.x - xv.x, dy = cv.y - xv.y, dz = cv.z - xv.z, dw = cv.w - xv.w;
        s = dx * dx + dy * dy + dz * dz + dw * dw;
        #pragma unroll
        for (int off = 32; off; off >>= 1) s += __shfl_xor(s, off, 64);
    }
    if (lane == 0) ps[wv] = s;
    __syncthreads();
    if (threadIdx.x == 0) {
        double p = (double)ps[0] + ps[1] + ps[2] + ps[3];
        atomicAdd(lsum, p);
        __threadfence();
        int done = atomicAdd(lcount, 1);
        if (done == nblocks - 1) {
            double tot = atomicAdd(lsum, 0.0);
            *out_loss = (float)(tot * inv_total);
        }
    }
}

// ---------------------------------------------------------------------------
// ---- f32 fallback path (round-2 proven) — only if ws too small ----
__global__ __launch_bounds__(256)
void k0_c2(const float4* __restrict__ cb4, const int* __restrict__ ridx,
           float* __restrict__ c2, int K, int kpad) {
    int k    = (int)(blockIdx.x * 4 + (threadIdx.x >> 6));
    int lane = threadIdx.x & 63;
    if (k >= kpad) return;
    double s = 0.0;
    if (k < K) {
        int row = ridx[k];
        float4 v = cb4[(size_t)row * D4 + lane];
        s = (double)v.x * v.x + (double)v.y * v.y
          + (double)v.z * v.z + (double)v.w * v.w;
    }
    #pragma unroll
    for (int off = 32; off; off >>= 1) s += __shfl_xor(s, off, 64);
    if (lane == 0) c2[k] = (k < K) ? (float)s : INFINITY;
}

__global__ __launch_bounds__(256, 2)
void fk1_argmin(const float4* __restrict__ x4, const float4* __restrict__ cb4,
                const int* __restrict__ ridx, const float* __restrict__ c2,
                float* __restrict__ pb1, float* __restrict__ pb2,
                int* __restrict__ pbi, int Ntok, int K, int kspan) {
    __shared__ float4 xs4[128 * 16];
    __shared__ float4 cs4[128 * 16];
    __shared__ float  c2_t[128];
    const int tid = threadIdx.x;
    const int r = tid >> 4, c = tid & 15;
    const int m0 = blockIdx.x * 128;
    const int kbase0 = blockIdx.y * kspan;
    float b1[8], b2[8]; int bi[8];
    #pragma unroll
    for (int i = 0; i < 8; ++i) { b1[i] = INFINITY; b2[i] = INFINITY; bi[i] = 0; }
    for (int t = 0; t < 8; ++t) {
        const int kbase = kbase0 + t * 128;
        if (kbase >= K) break;
        __syncthreads();
        if (tid < 128) c2_t[tid] = c2[kbase + tid];
        int cidx[8];
        #pragma unroll
        for (int q = 0; q < 8; ++q) {
            int k = kbase + 16 * q + r;
            cidx[q] = ridx[(k < K) ? k : 0];
        }
        float acc[8][8];
        #pragma unroll
        for (int i = 0; i < 8; ++i)
            #pragma unroll
            for (int j = 0; j < 8; ++j) acc[i][j] = 0.f;
        for (int ch = 0; ch < 4; ++ch) {
            __syncthreads();
            #pragma unroll
            for (int q = 0; q < 8; ++q) {
                int row = 16 * q + r;
                int p   = c ^ (row & 7);
                xs4[row * 16 + p] = x4[(size_t)(m0 + row) * D4 + ch * 16 + c];
                cs4[row * 16 + p] = cb4[(size_t)cidx[q] * D4 + ch * 16 + c];
            }
            __syncthreads();
            #pragma unroll 2
            for (int f = 0; f < 16; ++f) {
                float4 xf[8];
                #pragma unroll
                for (int i = 0; i < 8; ++i) xf[i] = xs4[(8 * r + i) * 16 + (f ^ i)];
                #pragma unroll
                for (int j = 0; j < 8; ++j) {
                    float4 cf = cs4[(c + 16 * j) * 16 + (f ^ (c & 7))];
                    #pragma unroll
                    for (int i = 0; i < 8; ++i) {
                        acc[i][j] = fmaf(xf[i].x, cf.x, acc[i][j]);
                        acc[i][j] = fmaf(xf[i].y, cf.y, acc[i][j]);
                        acc[i][j] = fmaf(xf[i].z, cf.z, acc[i][j]);
                        acc[i][j] = fmaf(xf[i].w, cf.w, acc[i][j]);
                    }
                }
            }
        }
        #pragma unroll
        for (int j = 0; j < 8; ++j) {
            float c2v = c2_t[c + 16 * j];
            int   k   = kbase + c + 16 * j;
            #pragma unroll
            for (int i = 0; i < 8; ++i) {
                float sc = fmaf(-2.f, acc[i][j], c2v);
                if (sc < b1[i]) { b2[i] = b1[i]; b1[i] = sc; bi[i] = k; }
                else            { b2[i] = fminf(b2[i], sc); }
            }
        }
    }
    __syncthreads();
    float* s1 = (float*)xs4;
    float* s2 = s1 + 128 * 16;
    int*   si = (int*)cs4;
    #pragma unroll
    for (int i = 0; i < 8; ++i) {
        int row = 8 * r + i;
        s1[row * 16 + c] = b1[i]; s2[row * 16 + c] = b2[i]; si[row * 16 + c] = bi[i];
    }
    __syncthreads();
    if (tid < 128) {
        float v1 = s1[tid * 16], v2 = s2[tid * 16];
        int   vi = si[tid * 16];
        #pragma unroll
        for (int cc = 1; cc < 16; ++cc) {
            float u1 = s1[tid * 16 + cc], u2 = s2[tid * 16 + cc];
            int   ui = si[tid * 16 + cc];
            if (u1 < v1 || (u1 == v1 && ui < vi)) { v2 = fminf(v1, u2); v1 = u1; vi = ui; }
            else                                  { v2 = fminf(v2, u1); }
        }
        size_t o = (size_t)blockIdx.y * Ntok + m0 + tid;
        pb1[o] = v1; pb2[o] = v2; pbi[o] = vi;
    }
}

// ---------------------------------------------------------------------------
extern "C" void kernel_launch(void* const* d_in, const int* in_sizes, int n_in,
                              void* d_out, int out_size, void* d_ws, size_t ws_size,
                              hipStream_t stream) {
    const float* x    = (const float*)d_in[0];
    const float* cb   = (const float*)d_in[1];
    const int*   ridx = (const int*)d_in[2];

    const int Ntok = in_sizes[0] / D;          // 16384
    const int K    = in_sizes[2];              // 3686

    float* out      = (float*)d_out;
    float* out_loss = out + (size_t)Ntok * D;
    float* out_idx  = out + (size_t)Ntok * D + 1;

    const float4* x4  = (const float4*)x;
    const float4* cb4 = (const float4*)cb;

    auto up = [](size_t v) { return (v + 255) & ~(size_t)255; };

    size_t need = 256 + up((size_t)KPAD * 512 * 2) + up((size_t)KPAD * 4)
                + 3 * up((size_t)NSPLIT * Ntok * 4) + 2 * up((size_t)Ntok * 4);

    const int gblocks = (Ntok + 3) / 4;
    const double inv_total = 1.0 / ((double)Ntok * (double)D);

    if (ws_size >= need && (Ntok & 127) == 0) {
        // ---------------- MFMA pipeline path ----------------
        char* w = (char*)d_ws;
        double* lsum   = (double*)w;
        int*    cnt    = (int*)(w + 8);
        int*    lcount = (int*)(w + 12);  w += 256;
        ushort* cpF   = (ushort*)w; w += up((size_t)KPAD * 512 * 2);
        float*  c2    = (float*)w;  w += up((size_t)KPAD * 4);
        float*  pb1   = (float*)w;  w += up((size_t)NSPLIT * Ntok * 4);
        float*  pb2   = (float*)w;  w += up((size_t)NSPLIT * Ntok * 4);
        int*    pbi   = (int*)w;    w += up((size_t)NSPLIT * Ntok * 4);
        int*    gidx  = (int*)w;    w += up((size_t)Ntok * 4);
        int*    tlist = (int*)w;

        ushort* xpF = (ushort*)d_out;   // 16.8 MB: exact fit in out_tok region

        const int nwav = 32 * (Ntok >> 5) + 32 * NEB + KPAD;

        hipMemsetAsync(d_ws, 0, 16, stream);
        p01_pack<<<dim3((nwav + 3) / 4), dim3(256), 0, stream>>>(
            x4, cb4, ridx, xpF, cpF, c2, Ntok, K);
        k1_mfma<<<dim3((Ntok / TMTOK) * NSPLIT), dim3(512), 0, stream>>>(
            xpF, cpF, c2, pb1, pb2, pbi, Ntok);
        k2_combine<<<dim3((Ntok + 255) / 256), dim3(256), 0, stream>>>(
            pb1, pb2, pbi, ridx, gidx, tlist, cnt, Ntok, NSPLIT);
        k_recheck<<<dim3(64), dim3(256), 0, stream>>>(
            x4, cb4, ridx, tlist, cnt, gidx, K);
        k3_gather_loss<<<dim3(gblocks), dim3(256), 0, stream>>>(
            x4, cb4, gidx, (float4*)out, out_idx, lsum, lcount, out_loss,
            Ntok, inv_total, gblocks);
    } else {
        // ---------------- f32 fallback (round-2 proven) ----------------
        const int kpad  = 4096;
        const int kspan = 1024;
        char* w = (char*)d_ws;
        double* lsum   = (double*)w;
        int*    cnt    = (int*)(w + 8);
        int*    lcount = (int*)(w + 12);  w += 256;
        float* c2    = (float*)w;  w += up((size_t)kpad * 4);
        float* pb1   = (float*)w;  w += up((size_t)4 * Ntok * 4);
        float* pb2   = (float*)w;  w += up((size_t)4 * Ntok * 4);
        int*   pbi   = (int*)w;    w += up((size_t)4 * Ntok * 4);
        int*   gidx  = (int*)w;    w += up((size_t)Ntok * 4);
        int*   tlist = (int*)w;

        hipMemsetAsync(d_ws, 0, 16, stream);
        k0_c2<<<dim3(kpad / 4), dim3(256), 0, stream>>>(cb4, ridx, c2, K, kpad);
        fk1_argmin<<<dim3(Ntok / 128, 4), dim3(256), 0, stream>>>(
            x4, cb4, ridx, c2, pb1, pb2, pbi, Ntok, K, kspan);
        k2_combine<<<dim3((Ntok + 255) / 256), dim3(256), 0, stream>>>(
            pb1, pb2, pbi, ridx, gidx, tlist, cnt, Ntok, 4);
        k_recheck<<<dim3(64), dim3(256), 0, stream>>>(
            x4, cb4, ridx, tlist, cnt, gidx, K);
        k3_gather_loss<<<dim3(gblocks), dim3(256), 0, stream>>>(
            x4, cb4, gidx, (float4*)out, out_idx, lsum, lcount, out_loss,
            Ntok, inv_total, gblocks);
    }
}

// Round 7
// 374.755 us; speedup vs baseline: 1.9326x; 1.5721x over previous
//
#include <hip/hip_runtime.h>
#include <math.h>

// Problem geometry: D=256 fixed; N, K from in_sizes.
#define D      256
#define D4     64
#define TAU    6.0e-3f   // near-tie margin; bf16-3-product score error ~2e-3

// ---- MFMA-path geometry ----
#define KPAD    4096     // padded subsampled-codebook size
#define NEB     128      // entry blocks of 32 (KPAD/32)
#define NSPLIT  8        // entry splits; kb = blockIdx.x & 7 -> XCD-pinned
#define KSPAN   512      // entries per block (one tile, no re-reads)
#define TMTOK   128      // tokens per block
#define NSTEPK  16       // k16-groups (D/16)
#define AFRAGS  32       // per step: 16 eb x {hi,lo}
#define BFRAGS  8        // per step: 4 tb x {hi,lo}
#define BUFU    ((AFRAGS + BFRAGS) * 512)   // ushorts per LDS buffer (40 KiB)

typedef short bf16x8 __attribute__((ext_vector_type(8)));
typedef float f32x16 __attribute__((ext_vector_type(16)));

#define GLD16(g, l) __builtin_amdgcn_global_load_lds( \
    (const __attribute__((address_space(1))) void*)(g), \
    (__attribute__((address_space(3))) void*)(l), 16, 0, 0)

__device__ inline ushort f2bf_rn(float f) {           // RNE f32 -> bf16 bits
    unsigned u = __float_as_uint(f);
    unsigned r = (u + 0x7fffu + ((u >> 16) & 1u)) >> 16;
    return (ushort)r;
}
__device__ inline float bf2f(ushort u) { return __uint_as_float(((unsigned)u) << 16); }
__device__ inline f32x16 zero16() {
    f32x16 z = {0,0,0,0,0,0,0,0,0,0,0,0,0,0,0,0};
    return z;
}
__device__ inline unsigned pack2(ushort a, ushort b) {
    return (unsigned)a | ((unsigned)b << 16);
}

// ---------------------------------------------------------------------------
// p01: fragment-major pack. xpF[kg][tb][512], cpF[kg][eb][512]:
// kg in [0,32): kg<16 = bf16hi of k16-group kg, kg>=16 = bf16lo of kg-16.
// Fragment: lane l -> row blk*32+(l&31), k'' = (l>>5)*8..+8 contiguous.
// Plus c2[k] (f64-exact, +inf pads). One wave per fragment / entry.
__global__ __launch_bounds__(256)
void p01_pack(const float4* __restrict__ x4, const float4* __restrict__ cb4,
              const int* __restrict__ ridx, ushort* __restrict__ xpF,
              ushort* __restrict__ cpF, float* __restrict__ c2,
              int Ntok, int K) {
    const int v    = (int)(blockIdx.x * 4 + (threadIdx.x >> 6));
    const int lane = threadIdx.x & 63;
    const int l31  = lane & 31, hi = lane >> 5;
    const int NTB  = Ntok >> 5;
    const int nx   = 32 * NTB;

    if (v < nx) {                                  // ---- x fragments ----
        int kg = v / NTB, tb = v - kg * NTB;
        int token = tb * 32 + l31;
        int f0 = (kg & 15) * 4 + hi * 2;           // float4 index
        float4 a = x4[(size_t)token * D4 + f0];
        float4 b = x4[(size_t)token * D4 + f0 + 1];
        float f[8] = {a.x, a.y, a.z, a.w, b.x, b.y, b.z, b.w};
        ushort u[8];
        if (kg < 16) {
            #pragma unroll
            for (int i = 0; i < 8; ++i) u[i] = f2bf_rn(f[i]);
        } else {
            #pragma unroll
            for (int i = 0; i < 8; ++i) {
                ushort hb = f2bf_rn(f[i]);
                u[i] = f2bf_rn(f[i] - bf2f(hb));
            }
        }
        uint4 o = {pack2(u[0],u[1]), pack2(u[2],u[3]),
                   pack2(u[4],u[5]), pack2(u[6],u[7])};
        *(uint4*)&xpF[((size_t)kg * NTB + tb) * 512 + lane * 8] = o;
        return;
    }
    int v2 = v - nx;
    if (v2 < 32 * NEB) {                           // ---- c fragments ----
        int kg = v2 >> 7, eb = v2 & (NEB - 1);
        int k = eb * 32 + l31;
        float f[8] = {0,0,0,0,0,0,0,0};
        if (k < K) {
            int row = ridx[k];
            int f0 = (kg & 15) * 4 + hi * 2;
            float4 a = cb4[(size_t)row * D4 + f0];
            float4 b = cb4[(size_t)row * D4 + f0 + 1];
            f[0]=a.x; f[1]=a.y; f[2]=a.z; f[3]=a.w;
            f[4]=b.x; f[5]=b.y; f[6]=b.z; f[7]=b.w;
        }
        ushort u[8];
        if (kg < 16) {
            #pragma unroll
            for (int i = 0; i < 8; ++i) u[i] = f2bf_rn(f[i]);
        } else {
            #pragma unroll
            for (int i = 0; i < 8; ++i) {
                ushort hb = f2bf_rn(f[i]);
                u[i] = f2bf_rn(f[i] - bf2f(hb));
            }
        }
        uint4 o = {pack2(u[0],u[1]), pack2(u[2],u[3]),
                   pack2(u[4],u[5]), pack2(u[6],u[7])};
        *(uint4*)&cpF[((size_t)kg * NEB + eb) * 512 + lane * 8] = o;
        return;
    }
    int k = v2 - 32 * NEB;                         // ---- c2 ----
    if (k >= KPAD) return;
    double s = 0.0;
    if (k < K) {
        int row = ridx[k];
        float4 vv = cb4[(size_t)row * D4 + lane];
        s = (double)vv.x * vv.x + (double)vv.y * vv.y
          + (double)vv.z * vv.z + (double)vv.w * vv.w;
    }
    #pragma unroll
    for (int off = 32; off; off >>= 1) s += __shfl_xor(s, off, 64);
    if (lane == 0) c2[k] = (k < K) ? (float)s : INFINITY;
}

// ---------------------------------------------------------------------------
// k1_mfma v4: single-barrier drift pipeline. Per step:
//   ds_read buf[s] (compiler fine-grained lgkmcnt) -> 24 MFMA ->
//   stage(s+2) -> vmcnt(5) [stage(s+1) landed, s+2 in flight] -> s_barrier.
// ds_read and MFMA share one inter-barrier window: waves drift, so the LDS
// read port serves late waves while early waves occupy the matrix pipes.
// Write-after-read safety: stage(s+2) overwrites buf[s-1], whose reads all
// completed before barrier(s-1) (SSA deps force waits before MFMA(s-1)).
__global__ __launch_bounds__(512, 2)
void k1_mfma(const ushort* __restrict__ xpF, const ushort* __restrict__ cpF,
             const float* __restrict__ c2,
             float* __restrict__ pb1, float* __restrict__ pb2,
             int* __restrict__ pbi, int Ntok) {
    __shared__ __align__(16) ushort lds[3 * BUFU];   // 120 KiB
    __shared__ float c2all[KSPAN];                   // 2 KiB

    const int tid  = threadIdx.x;
    const int w    = tid >> 6;         // 0..7
    const int lane = tid & 63;
    const int we   = w >> 1;           // 0..3: entry quarter (128 entries)
    const int wn   = w & 1;            // 0..1: token half (64 tokens)
    const int hi   = lane >> 5;
    const int l31  = lane & 31;
    const int NTB  = Ntok >> 5;

    const int raw = (int)blockIdx.x;
    const int kb  = raw & (NSPLIT - 1);        // XCD-pinned split
    const int m0  = (raw >> 3) * TMTOK;
    const int tb0 = m0 >> 5;
    const int e0s = kb * KSPAN;
    const int eb0 = e0s >> 5;

    c2all[tid] = c2[e0s + tid];                // tid < 512 == KSPAN

    auto stage = [&](int g, int buf) {
        ushort* A = &lds[buf * BUFU];
        ushort* B = A + AFRAGS * 512;
        #pragma unroll
        for (int j = 0; j < 4; ++j) {          // A: 32 frags / 8 waves
            int idx = w * 4 + j;
            int hl = idx >> 4, ebl = idx & 15;
            GLD16(cpF + ((size_t)(g + hl * 16) * NEB + eb0 + ebl) * 512 + lane * 8,
                  &A[idx * 512]);
        }
        {                                       // B: 8 frags / 8 waves
            int hl = w >> 2, tbl = w & 3;
            GLD16(xpF + ((size_t)(g + hl * 16) * NTB + tb0 + tbl) * 512 + lane * 8,
                  &B[w * 512]);
        }
    };

    f32x16 acc[4][2];
    #pragma unroll
    for (int et = 0; et < 4; ++et)
        #pragma unroll
        for (int tt = 0; tt < 2; ++tt) acc[et][tt] = zero16();

    // prologue: 2-deep prefetch, wait stage(0) only
    stage(0, 0);
    stage(1, 1);
    asm volatile("s_waitcnt vmcnt(5)" ::: "memory");
    __builtin_amdgcn_sched_barrier(0);
    __builtin_amdgcn_s_barrier();
    __builtin_amdgcn_sched_barrier(0);

    int bufr = 0;
    for (int s = 0; s < NSTEPK; ++s) {
        const ushort* A = &lds[bufr * BUFU];
        const ushort* B = A + AFRAGS * 512;
        bf16x8 ah[4], al[4], bh[2], bl[2];
        #pragma unroll
        for (int et = 0; et < 4; ++et) {
            ah[et] = *(const bf16x8*)&A[(we * 4 + et) * 512 + lane * 8];
            al[et] = *(const bf16x8*)&A[(16 + we * 4 + et) * 512 + lane * 8];
        }
        #pragma unroll
        for (int tt = 0; tt < 2; ++tt) {
            bh[tt] = *(const bf16x8*)&B[(wn * 2 + tt) * 512 + lane * 8];
            bl[tt] = *(const bf16x8*)&B[(4 + wn * 2 + tt) * 512 + lane * 8];
        }

        __builtin_amdgcn_s_setprio(1);
        #pragma unroll
        for (int et = 0; et < 4; ++et)
            #pragma unroll
            for (int tt = 0; tt < 2; ++tt) {
                acc[et][tt] = __builtin_amdgcn_mfma_f32_32x32x16_bf16(
                    ah[et], bh[tt], acc[et][tt], 0, 0, 0);
                acc[et][tt] = __builtin_amdgcn_mfma_f32_32x32x16_bf16(
                    al[et], bh[tt], acc[et][tt], 0, 0, 0);
                acc[et][tt] = __builtin_amdgcn_mfma_f32_32x32x16_bf16(
                    ah[et], bl[tt], acc[et][tt], 0, 0, 0);
            }
        __builtin_amdgcn_s_setprio(0);

        int sp = s + 2; if (sp > NSTEPK - 1) sp = NSTEPK - 1;  // uniform counts
        int bufc = bufr + 2; if (bufc >= 3) bufc -= 3;
        stage(sp, bufc);

        asm volatile("s_waitcnt vmcnt(5)" ::: "memory");   // stage(s+1) landed
        __builtin_amdgcn_sched_barrier(0);
        __builtin_amdgcn_s_barrier();                      // skew bound; buf[s] reads done chip-wide
        __builtin_amdgcn_sched_barrier(0);

        bufr = bufr + 1; if (bufr >= 3) bufr = 0;
    }

    // epilogue: scores + branchless top-2 (lexicographic tie-break)
    float b1[2] = {INFINITY, INFINITY}, b2[2] = {INFINITY, INFINITY};
    int   bi[2] = {0, 0};
    #pragma unroll
    for (int tt = 0; tt < 2; ++tt)
        #pragma unroll
        for (int et = 0; et < 4; ++et)
            #pragma unroll
            for (int r = 0; r < 16; ++r) {
                int rl = we * 128 + et * 32 + (r & 3) + 8 * (r >> 2) + 4 * hi;
                float sc = fmaf(-2.f, acc[et][tt][r], c2all[rl]);
                int   k  = e0s + rl;
                bool better = (sc < b1[tt]) || (sc == b1[tt] && k < bi[tt]);
                float nb2 = better ? b1[tt] : fminf(b2[tt], sc);
                b1[tt] = better ? sc : b1[tt];
                bi[tt] = better ? k  : bi[tt];
                b2[tt] = nb2;
            }

    // merge lane <-> lane^32 (complementary rows, same token col)
    #pragma unroll
    for (int tt = 0; tt < 2; ++tt) {
        float o1 = __shfl_xor(b1[tt], 32, 64);
        float o2 = __shfl_xor(b2[tt], 32, 64);
        int   oi = __shfl_xor(bi[tt], 32, 64);
        if (o1 < b1[tt] || (o1 == b1[tt] && oi < bi[tt])) {
            b2[tt] = fminf(b1[tt], o2); b1[tt] = o1; bi[tt] = oi;
        } else b2[tt] = fminf(b2[tt], o1);
    }

    __syncthreads();                       // drains tail loads; LDS reusable
    float* s1 = (float*)lds;               // [we 0..3][128 tokens]
    float* s2 = s1 + 512;
    int*   si = (int*)(s2 + 512);
    if (hi == 0) {
        #pragma unroll
        for (int tt = 0; tt < 2; ++tt) {
            int tl = wn * 64 + tt * 32 + l31;
            s1[we * 128 + tl] = b1[tt];
            s2[we * 128 + tl] = b2[tt];
            si[we * 128 + tl] = bi[tt];
        }
    }
    __syncthreads();
    if (tid < TMTOK) {
        float v1 = s1[tid], v2 = s2[tid]; int vi = si[tid];
        #pragma unroll
        for (int g = 1; g < 4; ++g) {
            float u1 = s1[g * 128 + tid], u2 = s2[g * 128 + tid];
            int   ui = si[g * 128 + tid];
            if (u1 < v1 || (u1 == v1 && ui < vi)) { v2 = fminf(v1, u2); v1 = u1; vi = ui; }
            else                                  { v2 = fminf(v2, u1); }
        }
        size_t o = (size_t)kb * Ntok + m0 + tid;
        pb1[o] = v1; pb2[o] = v2; pbi[o] = vi;
    }
}

// ---------------------------------------------------------------------------
// k2: combine splits per token; provisional global idx; flag near-ties.
__global__ __launch_bounds__(256)
void k2_combine(const float* __restrict__ pb1, const float* __restrict__ pb2,
                const int* __restrict__ pbi, const int* __restrict__ ridx,
                int* __restrict__ gidx, int* __restrict__ tlist,
                int* __restrict__ cnt, int Ntok, int nsplit) {
    int t = blockIdx.x * 256 + threadIdx.x;
    if (t >= Ntok) return;
    float v1 = INFINITY, v2 = INFINITY; int vi = 0x7fffffff;
    for (int kb = 0; kb < nsplit; ++kb) {
        size_t o = (size_t)kb * Ntok + t;
        float u1 = pb1[o], u2 = pb2[o]; int ui = pbi[o];
        if (u1 < v1 || (u1 == v1 && ui < vi)) { v2 = fminf(v1, u2); v1 = u1; vi = ui; }
        else                                  { v2 = fminf(v2, u1); }
    }
    gidx[t] = ridx[vi];
    if (v2 - v1 < TAU) {
        int pos = atomicAdd(cnt, 1);
        tlist[pos] = t;
    }
}

// ---------------------------------------------------------------------------
// k_recheck: exact f64 argmin, lexicographic tie-break, flagged tokens only.
__global__ __launch_bounds__(256)
void k_recheck(const float4* __restrict__ x4, const float4* __restrict__ cb4,
               const int* __restrict__ ridx, const int* __restrict__ tlist,
               const int* __restrict__ cnt, int* __restrict__ gidx, int K) {
    __shared__ float4 xls[D4];
    __shared__ double rv[256];
    __shared__ int    rix[256];
    const int tid = threadIdx.x;
    const int n   = *cnt;
    for (int fi = blockIdx.x; fi < n; fi += gridDim.x) {
        int t = tlist[fi];
        if (tid < D4) xls[tid] = x4[(size_t)t * D4 + tid];
        __syncthreads();
        double bv = INFINITY; int bi = 0x7fffffff;
        for (int k = tid; k < K; k += 256) {
            const float4* cr = cb4 + (size_t)ridx[k] * D4;
            double s = 0.0, cc = 0.0;
            #pragma unroll 4
            for (int d = 0; d < D4; ++d) {
                float4 cv = cr[d], xv = xls[d];
                s  = fma((double)cv.x, (double)xv.x, s);
                s  = fma((double)cv.y, (double)xv.y, s);
                s  = fma((double)cv.z, (double)xv.z, s);
                s  = fma((double)cv.w, (double)xv.w, s);
                cc = fma((double)cv.x, (double)cv.x, cc);
                cc = fma((double)cv.y, (double)cv.y, cc);
                cc = fma((double)cv.z, (double)cv.z, cc);
                cc = fma((double)cv.w, (double)cv.w, cc);
            }
            double sc = cc - 2.0 * s;
            if (sc < bv || (sc == bv && k < bi)) { bv = sc; bi = k; }
        }
        rv[tid] = bv; rix[tid] = bi;
        __syncthreads();
        for (int st = 128; st; st >>= 1) {
            if (tid < st) {
                double u = rv[tid + st]; int ui = rix[tid + st];
                if (u < rv[tid] || (u == rv[tid] && ui < rix[tid])) {
                    rv[tid] = u; rix[tid] = ui;
                }
            }
            __syncthreads();
        }
        if (tid == 0) gidx[t] = ridx[rix[0]];
        __syncthreads();
    }
}

// ---------------------------------------------------------------------------
// k3: gather codebook row per token, write tokens + float index + sq-err sum.
// (No atomics: contention-free; k4 reduces.)
__global__ __launch_bounds__(256)
void k3_gather(const float4* __restrict__ x4, const float4* __restrict__ cb4,
               const int* __restrict__ gidx, float4* __restrict__ out_tok,
               float* __restrict__ out_idx, float* __restrict__ tok_loss,
               int Ntok) {
    int t    = (int)(blockIdx.x * 4 + (threadIdx.x >> 6));
    int lane = threadIdx.x & 63;
    if (t >= Ntok) return;
    int g = gidx[t];
    float4 cv = cb4[(size_t)g * D4 + lane];
    float4 xv = x4[(size_t)t * D4 + lane];
    out_tok[(size_t)t * D4 + lane] = cv;
    if (lane == 0) out_idx[t] = (float)g;
    float dx = cv.x - xv.x, dy = cv.y - xv.y, dz = cv.z - xv.z, dw = cv.w - xv.w;
    float s = dx * dx + dy * dy + dz * dz + dw * dw;
    #pragma unroll
    for (int off = 32; off; off >>= 1) s += __shfl_xor(s, off, 64);
    if (lane == 0) tok_loss[t] = s;
}

// ---------------------------------------------------------------------------
// k4: deterministic fixed-order loss mean (single block).
__global__ __launch_bounds__(256)
void k4_loss(const float* __restrict__ tok_loss, float* __restrict__ out_loss,
             int Ntok, double inv_total) {
    __shared__ double sm[256];
    double s = 0.0;
    for (int i = threadIdx.x; i < Ntok; i += 256) s += (double)tok_loss[i];
    sm[threadIdx.x] = s;
    __syncthreads();
    for (int st = 128; st; st >>= 1) {
        if ((int)threadIdx.x < st) sm[threadIdx.x] += sm[threadIdx.x + st];
        __syncthreads();
    }
    if (threadIdx.x == 0) *out_loss = (float)(sm[0] * inv_total);
}

// ---------------------------------------------------------------------------
// ---- f32 fallback path (round-2 proven) — only if ws too small ----
__global__ __launch_bounds__(256)
void k0_c2(const float4* __restrict__ cb4, const int* __restrict__ ridx,
           float* __restrict__ c2, int K, int kpad) {
    int k    = (int)(blockIdx.x * 4 + (threadIdx.x >> 6));
    int lane = threadIdx.x & 63;
    if (k >= kpad) return;
    double s = 0.0;
    if (k < K) {
        int row = ridx[k];
        float4 v = cb4[(size_t)row * D4 + lane];
        s = (double)v.x * v.x + (double)v.y * v.y
          + (double)v.z * v.z + (double)v.w * v.w;
    }
    #pragma unroll
    for (int off = 32; off; off >>= 1) s += __shfl_xor(s, off, 64);
    if (lane == 0) c2[k] = (k < K) ? (float)s : INFINITY;
}

__global__ __launch_bounds__(256, 2)
void fk1_argmin(const float4* __restrict__ x4, const float4* __restrict__ cb4,
                const int* __restrict__ ridx, const float* __restrict__ c2,
                float* __restrict__ pb1, float* __restrict__ pb2,
                int* __restrict__ pbi, int Ntok, int K, int kspan) {
    __shared__ float4 xs4[128 * 16];
    __shared__ float4 cs4[128 * 16];
    __shared__ float  c2_t[128];
    const int tid = threadIdx.x;
    const int r = tid >> 4, c = tid & 15;
    const int m0 = blockIdx.x * 128;
    const int kbase0 = blockIdx.y * kspan;
    float b1[8], b2[8]; int bi[8];
    #pragma unroll
    for (int i = 0; i < 8; ++i) { b1[i] = INFINITY; b2[i] = INFINITY; bi[i] = 0; }
    for (int t = 0; t < 8; ++t) {
        const int kbase = kbase0 + t * 128;
        if (kbase >= K) break;
        __syncthreads();
        if (tid < 128) c2_t[tid] = c2[kbase + tid];
        int cidx[8];
        #pragma unroll
        for (int q = 0; q < 8; ++q) {
            int k = kbase + 16 * q + r;
            cidx[q] = ridx[(k < K) ? k : 0];
        }
        float acc[8][8];
        #pragma unroll
        for (int i = 0; i < 8; ++i)
            #pragma unroll
            for (int j = 0; j < 8; ++j) acc[i][j] = 0.f;
        for (int ch = 0; ch < 4; ++ch) {
            __syncthreads();
            #pragma unroll
            for (int q = 0; q < 8; ++q) {
                int row = 16 * q + r;
                int p   = c ^ (row & 7);
                xs4[row * 16 + p] = x4[(size_t)(m0 + row) * D4 + ch * 16 + c];
                cs4[row * 16 + p] = cb4[(size_t)cidx[q] * D4 + ch * 16 + c];
            }
            __syncthreads();
            #pragma unroll 2
            for (int f = 0; f < 16; ++f) {
                float4 xf[8];
                #pragma unroll
                for (int i = 0; i < 8; ++i) xf[i] = xs4[(8 * r + i) * 16 + (f ^ i)];
                #pragma unroll
                for (int j = 0; j < 8; ++j) {
                    float4 cf = cs4[(c + 16 * j) * 16 + (f ^ (c & 7))];
                    #pragma unroll
                    for (int i = 0; i < 8; ++i) {
                        acc[i][j] = fmaf(xf[i].x, cf.x, acc[i][j]);
                        acc[i][j] = fmaf(xf[i].y, cf.y, acc[i][j]);
                        acc[i][j] = fmaf(xf[i].z, cf.z, acc[i][j]);
                        acc[i][j] = fmaf(xf[i].w, cf.w, acc[i][j]);
                    }
                }
            }
        }
        #pragma unroll
        for (int j = 0; j < 8; ++j) {
            float c2v = c2_t[c + 16 * j];
            int   k   = kbase + c + 16 * j;
            #pragma unroll
            for (int i = 0; i < 8; ++i) {
                float sc = fmaf(-2.f, acc[i][j], c2v);
                if (sc < b1[i]) { b2[i] = b1[i]; b1[i] = sc; bi[i] = k; }
                else            { b2[i] = fminf(b2[i], sc); }
            }
        }
    }
    __syncthreads();
    float* s1 = (float*)xs4;
    float* s2 = s1 + 128 * 16;
    int*   si = (int*)cs4;
    #pragma unroll
    for (int i = 0; i < 8; ++i) {
        int row = 8 * r + i;
        s1[row * 16 + c] = b1[i]; s2[row * 16 + c] = b2[i]; si[row * 16 + c] = bi[i];
    }
    __syncthreads();
    if (tid < 128) {
        float v1 = s1[tid * 16], v2 = s2[tid * 16];
        int   vi = si[tid * 16];
        #pragma unroll
        for (int cc = 1; cc < 16; ++cc) {
            float u1 = s1[tid * 16 + cc], u2 = s2[tid * 16 + cc];
            int   ui = si[tid * 16 + cc];
            if (u1 < v1 || (u1 == v1 && ui < vi)) { v2 = fminf(v1, u2); v1 = u1; vi = ui; }
            else                                  { v2 = fminf(v2, u1); }
        }
        size_t o = (size_t)blockIdx.y * Ntok + m0 + tid;
        pb1[o] = v1; pb2[o] = v2; pbi[o] = vi;
    }
}

// ---------------------------------------------------------------------------
extern "C" void kernel_launch(void* const* d_in, const int* in_sizes, int n_in,
                              void* d_out, int out_size, void* d_ws, size_t ws_size,
                              hipStream_t stream) {
    const float* x    = (const float*)d_in[0];
    const float* cb   = (const float*)d_in[1];
    const int*   ridx = (const int*)d_in[2];

    const int Ntok = in_sizes[0] / D;          // 16384
    const int K    = in_sizes[2];              // 3686

    float* out      = (float*)d_out;
    float* out_loss = out + (size_t)Ntok * D;
    float* out_idx  = out + (size_t)Ntok * D + 1;

    const float4* x4  = (const float4*)x;
    const float4* cb4 = (const float4*)cb;

    auto up = [](size_t v) { return (v + 255) & ~(size_t)255; };

    size_t need = 256 + up((size_t)KPAD * 512 * 2) + up((size_t)KPAD * 4)
                + 3 * up((size_t)NSPLIT * Ntok * 4) + 3 * up((size_t)Ntok * 4);

    const int gblocks = (Ntok + 3) / 4;
    const double inv_total = 1.0 / ((double)Ntok * (double)D);

    if (ws_size >= need && (Ntok & 127) == 0) {
        // ---------------- MFMA pipeline path ----------------
        char* w = (char*)d_ws;
        int*    cnt   = (int*)w;    w += 256;
        ushort* cpF   = (ushort*)w; w += up((size_t)KPAD * 512 * 2);
        float*  c2    = (float*)w;  w += up((size_t)KPAD * 4);
        float*  pb1   = (float*)w;  w += up((size_t)NSPLIT * Ntok * 4);
        float*  pb2   = (float*)w;  w += up((size_t)NSPLIT * Ntok * 4);
        int*    pbi   = (int*)w;    w += up((size_t)NSPLIT * Ntok * 4);
        int*    gidx  = (int*)w;    w += up((size_t)Ntok * 4);
        int*    tlist = (int*)w;    w += up((size_t)Ntok * 4);
        float*  tl    = (float*)w;

        ushort* xpF = (ushort*)d_out;   // 16.8 MB: exact fit in out_tok region

        const int nwav = 32 * (Ntok >> 5) + 32 * NEB + KPAD;

        hipMemsetAsync(cnt, 0, 4, stream);
        p01_pack<<<dim3((nwav + 3) / 4), dim3(256), 0, stream>>>(
            x4, cb4, ridx, xpF, cpF, c2, Ntok, K);
        k1_mfma<<<dim3((Ntok / TMTOK) * NSPLIT), dim3(512), 0, stream>>>(
            xpF, cpF, c2, pb1, pb2, pbi, Ntok);
        k2_combine<<<dim3((Ntok + 255) / 256), dim3(256), 0, stream>>>(
            pb1, pb2, pbi, ridx, gidx, tlist, cnt, Ntok, NSPLIT);
        k_recheck<<<dim3(256), dim3(256), 0, stream>>>(
            x4, cb4, ridx, tlist, cnt, gidx, K);
        k3_gather<<<dim3(gblocks), dim3(256), 0, stream>>>(
            x4, cb4, gidx, (float4*)out, out_idx, tl, Ntok);
        k4_loss<<<dim3(1), dim3(256), 0, stream>>>(tl, out_loss, Ntok, inv_total);
    } else {
        // ---------------- f32 fallback (round-2 proven) ----------------
        const int kpad  = 4096;
        const int kspan = 1024;
        char* w = (char*)d_ws;
        int*   cnt   = (int*)w;    w += 256;
        float* c2    = (float*)w;  w += up((size_t)kpad * 4);
        float* pb1   = (float*)w;  w += up((size_t)4 * Ntok * 4);
        float* pb2   = (float*)w;  w += up((size_t)4 * Ntok * 4);
        int*   pbi   = (int*)w;    w += up((size_t)4 * Ntok * 4);
        int*   gidx  = (int*)w;    w += up((size_t)Ntok * 4);
        int*   tlist = (int*)w;    w += up((size_t)Ntok * 4);
        float* tl    = (float*)w;

        hipMemsetAsync(cnt, 0, 4, stream);
        k0_c2<<<dim3(kpad / 4), dim3(256), 0, stream>>>(cb4, ridx, c2, K, kpad);
        fk1_argmin<<<dim3(Ntok / 128, 4), dim3(256), 0, stream>>>(
            x4, cb4, ridx, c2, pb1, pb2, pbi, Ntok, K, kspan);
        k2_combine<<<dim3((Ntok + 255) / 256), dim3(256), 0, stream>>>(
            pb1, pb2, pbi, ridx, gidx, tlist, cnt, Ntok, 4);
        k_recheck<<<dim3(256), dim3(256), 0, stream>>>(
            x4, cb4, ridx, tlist, cnt, gidx, K);
        k3_gather<<<dim3(gblocks), dim3(256), 0, stream>>>(
            x4, cb4, gidx, (float4*)out, out_idx, tl, Ntok);
        k4_loss<<<dim3(1), dim3(256), 0, stream>>>(tl, out_loss, Ntok, inv_total);
    }
}

// Round 8
// 314.376 us; speedup vs baseline: 2.3037x; 1.1921x over previous
//
#include <hip/hip_runtime.h>
#include <math.h>

// Problem geometry: D=256 fixed; N, K from in_sizes.
#define D      256
#define D4     64
#define TAU    6.0e-3f   // near-tie margin; bf16-3-product score error ~2e-3

// ---- MFMA-path geometry (round 8: occupancy) ----
#define KPAD    4096     // padded subsampled-codebook size
#define NEB     128      // entry blocks of 32 (KPAD/32)
#define NSPLIT  16       // entry splits; kb = blockIdx.x & 15 (kb, kb+8 same XCD)
#define KSPAN   256      // entries per block
#define TMTOK   128      // tokens per block
#define NSTEPK  16       // k16-groups (D/16)
#define AFRAGS  16       // per step: 8 eb x {hi,lo}
#define BFRAGS  8        // per step: 4 tb x {hi,lo}
#define BUFU    ((AFRAGS + BFRAGS) * 512)   // ushorts per LDS buffer (24 KiB)

typedef short bf16x8 __attribute__((ext_vector_type(8)));
typedef float f32x16 __attribute__((ext_vector_type(16)));

#define GLD16(g, l) __builtin_amdgcn_global_load_lds( \
    (const __attribute__((address_space(1))) void*)(g), \
    (__attribute__((address_space(3))) void*)(l), 16, 0, 0)

__device__ inline ushort f2bf_rn(float f) {           // RNE f32 -> bf16 bits
    unsigned u = __float_as_uint(f);
    unsigned r = (u + 0x7fffu + ((u >> 16) & 1u)) >> 16;
    return (ushort)r;
}
__device__ inline float bf2f(ushort u) { return __uint_as_float(((unsigned)u) << 16); }
__device__ inline f32x16 zero16() {
    f32x16 z = {0,0,0,0,0,0,0,0,0,0,0,0,0,0,0,0};
    return z;
}
__device__ inline unsigned pack2(ushort a, ushort b) {
    return (unsigned)a | ((unsigned)b << 16);
}

// ---------------------------------------------------------------------------
// p01: fragment-major pack. xpF[kg][tb][512], cpF[kg][eb][512]:
// kg in [0,32): kg<16 = bf16hi of k16-group kg, kg>=16 = bf16lo of kg-16.
// Fragment: lane l -> row blk*32+(l&31), k'' = (l>>5)*8..+8 contiguous.
// Plus c2[k] (f64-exact, +inf pads). One wave per fragment / entry.
__global__ __launch_bounds__(256)
void p01_pack(const float4* __restrict__ x4, const float4* __restrict__ cb4,
              const int* __restrict__ ridx, ushort* __restrict__ xpF,
              ushort* __restrict__ cpF, float* __restrict__ c2,
              int Ntok, int K) {
    const int v    = (int)(blockIdx.x * 4 + (threadIdx.x >> 6));
    const int lane = threadIdx.x & 63;
    const int l31  = lane & 31, hi = lane >> 5;
    const int NTB  = Ntok >> 5;
    const int nx   = 32 * NTB;

    if (v < nx) {                                  // ---- x fragments ----
        int kg = v / NTB, tb = v - kg * NTB;
        int token = tb * 32 + l31;
        int f0 = (kg & 15) * 4 + hi * 2;           // float4 index
        float4 a = x4[(size_t)token * D4 + f0];
        float4 b = x4[(size_t)token * D4 + f0 + 1];
        float f[8] = {a.x, a.y, a.z, a.w, b.x, b.y, b.z, b.w};
        ushort u[8];
        if (kg < 16) {
            #pragma unroll
            for (int i = 0; i < 8; ++i) u[i] = f2bf_rn(f[i]);
        } else {
            #pragma unroll
            for (int i = 0; i < 8; ++i) {
                ushort hb = f2bf_rn(f[i]);
                u[i] = f2bf_rn(f[i] - bf2f(hb));
            }
        }
        uint4 o = {pack2(u[0],u[1]), pack2(u[2],u[3]),
                   pack2(u[4],u[5]), pack2(u[6],u[7])};
        *(uint4*)&xpF[((size_t)kg * NTB + tb) * 512 + lane * 8] = o;
        return;
    }
    int v2 = v - nx;
    if (v2 < 32 * NEB) {                           // ---- c fragments ----
        int kg = v2 >> 7, eb = v2 & (NEB - 1);
        int k = eb * 32 + l31;
        float f[8] = {0,0,0,0,0,0,0,0};
        if (k < K) {
            int row = ridx[k];
            int f0 = (kg & 15) * 4 + hi * 2;
            float4 a = cb4[(size_t)row * D4 + f0];
            float4 b = cb4[(size_t)row * D4 + f0 + 1];
            f[0]=a.x; f[1]=a.y; f[2]=a.z; f[3]=a.w;
            f[4]=b.x; f[5]=b.y; f[6]=b.z; f[7]=b.w;
        }
        ushort u[8];
        if (kg < 16) {
            #pragma unroll
            for (int i = 0; i < 8; ++i) u[i] = f2bf_rn(f[i]);
        } else {
            #pragma unroll
            for (int i = 0; i < 8; ++i) {
                ushort hb = f2bf_rn(f[i]);
                u[i] = f2bf_rn(f[i] - bf2f(hb));
            }
        }
        uint4 o = {pack2(u[0],u[1]), pack2(u[2],u[3]),
                   pack2(u[4],u[5]), pack2(u[6],u[7])};
        *(uint4*)&cpF[((size_t)kg * NEB + eb) * 512 + lane * 8] = o;
        return;
    }
    int k = v2 - 32 * NEB;                         // ---- c2 ----
    if (k >= KPAD) return;
    double s = 0.0;
    if (k < K) {
        int row = ridx[k];
        float4 vv = cb4[(size_t)row * D4 + lane];
        s = (double)vv.x * vv.x + (double)vv.y * vv.y
          + (double)vv.z * vv.z + (double)vv.w * vv.w;
    }
    #pragma unroll
    for (int off = 32; off; off >>= 1) s += __shfl_xor(s, off, 64);
    if (lane == 0) c2[k] = (k < K) ? (float)s : INFINITY;
}

// ---------------------------------------------------------------------------
// k1_mfma v5: 8 waves, 128 tok x 256 ent, 24 KB x3 LDS buffers -> 2 blocks/CU
// (16 waves/CU, 4/SIMD). Cross-block overlap hides the per-step vmcnt+barrier
// drain (m114/m97 mechanism). Single-barrier counted-vmcnt(3) loop as r7.
__global__ __launch_bounds__(512, 4)
void k1_mfma(const ushort* __restrict__ xpF, const ushort* __restrict__ cpF,
             const float* __restrict__ c2,
             float* __restrict__ pb1, float* __restrict__ pb2,
             int* __restrict__ pbi, int Ntok) {
    __shared__ __align__(16) ushort lds[3 * BUFU];   // 72 KiB
    __shared__ float c2all[KSPAN];                   // 1 KiB

    const int tid  = threadIdx.x;
    const int w    = tid >> 6;         // 0..7
    const int lane = tid & 63;
    const int we   = w >> 1;           // 0..3: entry quarter (64 entries)
    const int wn   = w & 1;            // 0..1: token half (64 tokens)
    const int hi   = lane >> 5;
    const int l31  = lane & 31;
    const int NTB  = Ntok >> 5;

    const int raw = (int)blockIdx.x;
    const int kb  = raw & (NSPLIT - 1);        // kb, kb+8 -> same XCD, adjacent
    const int m0  = (raw >> 4) * TMTOK;
    const int tb0 = m0 >> 5;
    const int e0s = kb * KSPAN;
    const int eb0 = e0s >> 5;

    if (tid < KSPAN) c2all[tid] = c2[e0s + tid];

    auto stage = [&](int g, int buf) {
        ushort* A = &lds[buf * BUFU];
        ushort* B = A + AFRAGS * 512;
        #pragma unroll
        for (int j = 0; j < 2; ++j) {          // A: 16 frags / 8 waves
            int idx = w * 2 + j;
            int hl = idx >> 3, ebl = idx & 7;
            GLD16(cpF + ((size_t)(g + hl * 16) * NEB + eb0 + ebl) * 512 + lane * 8,
                  &A[idx * 512]);
        }
        {                                       // B: 8 frags / 8 waves
            int hl = w >> 2, tbl = w & 3;
            GLD16(xpF + ((size_t)(g + hl * 16) * NTB + tb0 + tbl) * 512 + lane * 8,
                  &B[w * 512]);
        }
    };

    f32x16 acc[2][2];
    #pragma unroll
    for (int et = 0; et < 2; ++et)
        #pragma unroll
        for (int tt = 0; tt < 2; ++tt) acc[et][tt] = zero16();

    // prologue: 2-deep prefetch, wait stage(0) only (3 loads/wave/stage)
    stage(0, 0);
    stage(1, 1);
    asm volatile("s_waitcnt vmcnt(3)" ::: "memory");
    __builtin_amdgcn_sched_barrier(0);
    __builtin_amdgcn_s_barrier();
    __builtin_amdgcn_sched_barrier(0);

    int bufr = 0;
    for (int s = 0; s < NSTEPK; ++s) {
        const ushort* A = &lds[bufr * BUFU];
        const ushort* B = A + AFRAGS * 512;
        bf16x8 ah[2], al[2], bh[2], bl[2];
        #pragma unroll
        for (int et = 0; et < 2; ++et) {
            ah[et] = *(const bf16x8*)&A[(we * 2 + et) * 512 + lane * 8];
            al[et] = *(const bf16x8*)&A[(8 + we * 2 + et) * 512 + lane * 8];
        }
        #pragma unroll
        for (int tt = 0; tt < 2; ++tt) {
            bh[tt] = *(const bf16x8*)&B[(wn * 2 + tt) * 512 + lane * 8];
            bl[tt] = *(const bf16x8*)&B[(4 + wn * 2 + tt) * 512 + lane * 8];
        }

        __builtin_amdgcn_s_setprio(1);
        #pragma unroll
        for (int et = 0; et < 2; ++et)
            #pragma unroll
            for (int tt = 0; tt < 2; ++tt) {
                acc[et][tt] = __builtin_amdgcn_mfma_f32_32x32x16_bf16(
                    ah[et], bh[tt], acc[et][tt], 0, 0, 0);
                acc[et][tt] = __builtin_amdgcn_mfma_f32_32x32x16_bf16(
                    al[et], bh[tt], acc[et][tt], 0, 0, 0);
                acc[et][tt] = __builtin_amdgcn_mfma_f32_32x32x16_bf16(
                    ah[et], bl[tt], acc[et][tt], 0, 0, 0);
            }
        __builtin_amdgcn_s_setprio(0);

        int sp = s + 2; if (sp > NSTEPK - 1) sp = NSTEPK - 1;  // uniform counts
        int bufc = bufr + 2; if (bufc >= 3) bufc -= 3;
        stage(sp, bufc);

        asm volatile("s_waitcnt vmcnt(3)" ::: "memory");   // stage(s+1) landed
        __builtin_amdgcn_sched_barrier(0);
        __builtin_amdgcn_s_barrier();                      // buf[s] reads done block-wide
        __builtin_amdgcn_sched_barrier(0);

        bufr = bufr + 1; if (bufr >= 3) bufr = 0;
    }

    // epilogue: scores + branchless top-2 (lexicographic tie-break)
    float b1[2] = {INFINITY, INFINITY}, b2[2] = {INFINITY, INFINITY};
    int   bi[2] = {0, 0};
    #pragma unroll
    for (int tt = 0; tt < 2; ++tt)
        #pragma unroll
        for (int et = 0; et < 2; ++et)
            #pragma unroll
            for (int r = 0; r < 16; ++r) {
                int rl = we * 64 + et * 32 + (r & 3) + 8 * (r >> 2) + 4 * hi;
                float sc = fmaf(-2.f, acc[et][tt][r], c2all[rl]);
                int   k  = e0s + rl;
                bool better = (sc < b1[tt]) || (sc == b1[tt] && k < bi[tt]);
                float nb2 = better ? b1[tt] : fminf(b2[tt], sc);
                b1[tt] = better ? sc : b1[tt];
                bi[tt] = better ? k  : bi[tt];
                b2[tt] = nb2;
            }

    // merge lane <-> lane^32 (complementary rows, same token col)
    #pragma unroll
    for (int tt = 0; tt < 2; ++tt) {
        float o1 = __shfl_xor(b1[tt], 32, 64);
        float o2 = __shfl_xor(b2[tt], 32, 64);
        int   oi = __shfl_xor(bi[tt], 32, 64);
        if (o1 < b1[tt] || (o1 == b1[tt] && oi < bi[tt])) {
            b2[tt] = fminf(b1[tt], o2); b1[tt] = o1; bi[tt] = oi;
        } else b2[tt] = fminf(b2[tt], o1);
    }

    __syncthreads();                       // drains tail loads; LDS reusable
    float* s1 = (float*)lds;               // [we 0..3][128 tokens]
    float* s2 = s1 + 512;
    int*   si = (int*)(s2 + 512);
    if (hi == 0) {
        #pragma unroll
        for (int tt = 0; tt < 2; ++tt) {
            int tl = wn * 64 + tt * 32 + l31;
            s1[we * 128 + tl] = b1[tt];
            s2[we * 128 + tl] = b2[tt];
            si[we * 128 + tl] = bi[tt];
        }
    }
    __syncthreads();
    if (tid < TMTOK) {
        float v1 = s1[tid], v2 = s2[tid]; int vi = si[tid];
        #pragma unroll
        for (int g = 1; g < 4; ++g) {
            float u1 = s1[g * 128 + tid], u2 = s2[g * 128 + tid];
            int   ui = si[g * 128 + tid];
            if (u1 < v1 || (u1 == v1 && ui < vi)) { v2 = fminf(v1, u2); v1 = u1; vi = ui; }
            else                                  { v2 = fminf(v2, u1); }
        }
        size_t o = (size_t)kb * Ntok + m0 + tid;
        pb1[o] = v1; pb2[o] = v2; pbi[o] = vi;
    }
}

// ---------------------------------------------------------------------------
// k2: combine splits per token; provisional global idx; flag near-ties.
__global__ __launch_bounds__(256)
void k2_combine(const float* __restrict__ pb1, const float* __restrict__ pb2,
                const int* __restrict__ pbi, const int* __restrict__ ridx,
                int* __restrict__ gidx, int* __restrict__ tlist,
                int* __restrict__ cnt, int Ntok, int nsplit) {
    int t = blockIdx.x * 256 + threadIdx.x;
    if (t >= Ntok) return;
    float v1 = INFINITY, v2 = INFINITY; int vi = 0x7fffffff;
    for (int kb = 0; kb < nsplit; ++kb) {
        size_t o = (size_t)kb * Ntok + t;
        float u1 = pb1[o], u2 = pb2[o]; int ui = pbi[o];
        if (u1 < v1 || (u1 == v1 && ui < vi)) { v2 = fminf(v1, u2); v1 = u1; vi = ui; }
        else                                  { v2 = fminf(v2, u1); }
    }
    gidx[t] = ridx[vi];
    if (v2 - v1 < TAU) {
        int pos = atomicAdd(cnt, 1);
        tlist[pos] = t;
    }
}

// ---------------------------------------------------------------------------
// k_recheck: exact f64 argmin, lexicographic tie-break, flagged tokens only.
__global__ __launch_bounds__(256)
void k_recheck(const float4* __restrict__ x4, const float4* __restrict__ cb4,
               const int* __restrict__ ridx, const int* __restrict__ tlist,
               const int* __restrict__ cnt, int* __restrict__ gidx, int K) {
    __shared__ float4 xls[D4];
    __shared__ double rv[256];
    __shared__ int    rix[256];
    const int tid = threadIdx.x;
    const int n   = *cnt;
    for (int fi = blockIdx.x; fi < n; fi += gridDim.x) {
        int t = tlist[fi];
        if (tid < D4) xls[tid] = x4[(size_t)t * D4 + tid];
        __syncthreads();
        double bv = INFINITY; int bi = 0x7fffffff;
        for (int k = tid; k < K; k += 256) {
            const float4* cr = cb4 + (size_t)ridx[k] * D4;
            double s = 0.0, cc = 0.0;
            #pragma unroll 4
            for (int d = 0; d < D4; ++d) {
                float4 cv = cr[d], xv = xls[d];
                s  = fma((double)cv.x, (double)xv.x, s);
                s  = fma((double)cv.y, (double)xv.y, s);
                s  = fma((double)cv.z, (double)xv.z, s);
                s  = fma((double)cv.w, (double)xv.w, s);
                cc = fma((double)cv.x, (double)cv.x, cc);
                cc = fma((double)cv.y, (double)cv.y, cc);
                cc = fma((double)cv.z, (double)cv.z, cc);
                cc = fma((double)cv.w, (double)cv.w, cc);
            }
            double sc = cc - 2.0 * s;
            if (sc < bv || (sc == bv && k < bi)) { bv = sc; bi = k; }
        }
        rv[tid] = bv; rix[tid] = bi;
        __syncthreads();
        for (int st = 128; st; st >>= 1) {
            if (tid < st) {
                double u = rv[tid + st]; int ui = rix[tid + st];
                if (u < rv[tid] || (u == rv[tid] && ui < rix[tid])) {
                    rv[tid] = u; rix[tid] = ui;
                }
            }
            __syncthreads();
        }
        if (tid == 0) gidx[t] = ridx[rix[0]];
        __syncthreads();
    }
}

// ---------------------------------------------------------------------------
// k3: gather codebook row per token, write tokens + float index + sq-err sum.
__global__ __launch_bounds__(256)
void k3_gather(const float4* __restrict__ x4, const float4* __restrict__ cb4,
               const int* __restrict__ gidx, float4* __restrict__ out_tok,
               float* __restrict__ out_idx, float* __restrict__ tok_loss,
               int Ntok) {
    int t    = (int)(blockIdx.x * 4 + (threadIdx.x >> 6));
    int lane = threadIdx.x & 63;
    if (t >= Ntok) return;
    int g = gidx[t];
    float4 cv = cb4[(size_t)g * D4 + lane];
    float4 xv = x4[(size_t)t * D4 + lane];
    out_tok[(size_t)t * D4 + lane] = cv;
    if (lane == 0) out_idx[t] = (float)g;
    float dx = cv.x - xv.x, dy = cv.y - xv.y, dz = cv.z - xv.z, dw = cv.w - xv.w;
    float s = dx * dx + dy * dy + dz * dz + dw * dw;
    #pragma unroll
    for (int off = 32; off; off >>= 1) s += __shfl_xor(s, off, 64);
    if (lane == 0) tok_loss[t] = s;
}

// ---------------------------------------------------------------------------
// k4: deterministic fixed-order loss mean (single block).
__global__ __launch_bounds__(256)
void k4_loss(const float* __restrict__ tok_loss, float* __restrict__ out_loss,
             int Ntok, double inv_total) {
    __shared__ double sm[256];
    double s = 0.0;
    for (int i = threadIdx.x; i < Ntok; i += 256) s += (double)tok_loss[i];
    sm[threadIdx.x] = s;
    __syncthreads();
    for (int st = 128; st; st >>= 1) {
        if ((int)threadIdx.x < st) sm[threadIdx.x] += sm[threadIdx.x + st];
        __syncthreads();
    }
    if (threadIdx.x == 0) *out_loss = (float)(sm[0] * inv_total);
}

// ---------------------------------------------------------------------------
// ---- f32 fallback path (round-2 proven) — only if ws too small ----
__global__ __launch_bounds__(256)
void k0_c2(const float4* __restrict__ cb4, const int* __restrict__ ridx,
           float* __restrict__ c2, int K, int kpad) {
    int k    = (int)(blockIdx.x * 4 + (threadIdx.x >> 6));
    int lane = threadIdx.x & 63;
    if (k >= kpad) return;
    double s = 0.0;
    if (k < K) {
        int row = ridx[k];
        float4 v = cb4[(size_t)row * D4 + lane];
        s = (double)v.x * v.x + (double)v.y * v.y
          + (double)v.z * v.z + (double)v.w * v.w;
    }
    #pragma unroll
    for (int off = 32; off; off >>= 1) s += __shfl_xor(s, off, 64);
    if (lane == 0) c2[k] = (k < K) ? (float)s : INFINITY;
}

__global__ __launch_bounds__(256, 2)
void fk1_argmin(const float4* __restrict__ x4, const float4* __restrict__ cb4,
                const int* __restrict__ ridx, const float* __restrict__ c2,
                float* __restrict__ pb1, float* __restrict__ pb2,
                int* __restrict__ pbi, int Ntok, int K, int kspan) {
    __shared__ float4 xs4[128 * 16];
    __shared__ float4 cs4[128 * 16];
    __shared__ float  c2_t[128];
    const int tid = threadIdx.x;
    const int r = tid >> 4, c = tid & 15;
    const int m0 = blockIdx.x * 128;
    const int kbase0 = blockIdx.y * kspan;
    float b1[8], b2[8]; int bi[8];
    #pragma unroll
    for (int i = 0; i < 8; ++i) { b1[i] = INFINITY; b2[i] = INFINITY; bi[i] = 0; }
    for (int t = 0; t < 8; ++t) {
        const int kbase = kbase0 + t * 128;
        if (kbase >= K) break;
        __syncthreads();
        if (tid < 128) c2_t[tid] = c2[kbase + tid];
        int cidx[8];
        #pragma unroll
        for (int q = 0; q < 8; ++q) {
            int k = kbase + 16 * q + r;
            cidx[q] = ridx[(k < K) ? k : 0];
        }
        float acc[8][8];
        #pragma unroll
        for (int i = 0; i < 8; ++i)
            #pragma unroll
            for (int j = 0; j < 8; ++j) acc[i][j] = 0.f;
        for (int ch = 0; ch < 4; ++ch) {
            __syncthreads();
            #pragma unroll
            for (int q = 0; q < 8; ++q) {
                int row = 16 * q + r;
                int p   = c ^ (row & 7);
                xs4[row * 16 + p] = x4[(size_t)(m0 + row) * D4 + ch * 16 + c];
                cs4[row * 16 + p] = cb4[(size_t)cidx[q] * D4 + ch * 16 + c];
            }
            __syncthreads();
            #pragma unroll 2
            for (int f = 0; f < 16; ++f) {
                float4 xf[8];
                #pragma unroll
                for (int i = 0; i < 8; ++i) xf[i] = xs4[(8 * r + i) * 16 + (f ^ i)];
                #pragma unroll
                for (int j = 0; j < 8; ++j) {
                    float4 cf = cs4[(c + 16 * j) * 16 + (f ^ (c & 7))];
                    #pragma unroll
                    for (int i = 0; i < 8; ++i) {
                        acc[i][j] = fmaf(xf[i].x, cf.x, acc[i][j]);
                        acc[i][j] = fmaf(xf[i].y, cf.y, acc[i][j]);
                        acc[i][j] = fmaf(xf[i].z, cf.z, acc[i][j]);
                        acc[i][j] = fmaf(xf[i].w, cf.w, acc[i][j]);
                    }
                }
            }
        }
        #pragma unroll
        for (int j = 0; j < 8; ++j) {
            float c2v = c2_t[c + 16 * j];
            int   k   = kbase + c + 16 * j;
            #pragma unroll
            for (int i = 0; i < 8; ++i) {
                float sc = fmaf(-2.f, acc[i][j], c2v);
                if (sc < b1[i]) { b2[i] = b1[i]; b1[i] = sc; bi[i] = k; }
                else            { b2[i] = fminf(b2[i], sc); }
            }
        }
    }
    __syncthreads();
    float* s1 = (float*)xs4;
    float* s2 = s1 + 128 * 16;
    int*   si = (int*)cs4;
    #pragma unroll
    for (int i = 0; i < 8; ++i) {
        int row = 8 * r + i;
        s1[row * 16 + c] = b1[i]; s2[row * 16 + c] = b2[i]; si[row * 16 + c] = bi[i];
    }
    __syncthreads();
    if (tid < 128) {
        float v1 = s1[tid * 16], v2 = s2[tid * 16];
        int   vi = si[tid * 16];
        #pragma unroll
        for (int cc = 1; cc < 16; ++cc) {
            float u1 = s1[tid * 16 + cc], u2 = s2[tid * 16 + cc];
            int   ui = si[tid * 16 + cc];
            if (u1 < v1 || (u1 == v1 && ui < vi)) { v2 = fminf(v1, u2); v1 = u1; vi = ui; }
            else                                  { v2 = fminf(v2, u1); }
        }
        size_t o = (size_t)blockIdx.y * Ntok + m0 + tid;
        pb1[o] = v1; pb2[o] = v2; pbi[o] = vi;
    }
}

// ---------------------------------------------------------------------------
extern "C" void kernel_launch(void* const* d_in, const int* in_sizes, int n_in,
                              void* d_out, int out_size, void* d_ws, size_t ws_size,
                              hipStream_t stream) {
    const float* x    = (const float*)d_in[0];
    const float* cb   = (const float*)d_in[1];
    const int*   ridx = (const int*)d_in[2];

    const int Ntok = in_sizes[0] / D;          // 16384
    const int K    = in_sizes[2];              // 3686

    float* out      = (float*)d_out;
    float* out_loss = out + (size_t)Ntok * D;
    float* out_idx  = out + (size_t)Ntok * D + 1;

    const float4* x4  = (const float4*)x;
    const float4* cb4 = (const float4*)cb;

    auto up = [](size_t v) { return (v + 255) & ~(size_t)255; };

    size_t need = 256 + up((size_t)KPAD * 512 * 2) + up((size_t)KPAD * 4)
                + 3 * up((size_t)NSPLIT * Ntok * 4) + 3 * up((size_t)Ntok * 4);

    const int gblocks = (Ntok + 3) / 4;
    const double inv_total = 1.0 / ((double)Ntok * (double)D);

    if (ws_size >= need && (Ntok & 127) == 0) {
        // ---------------- MFMA pipeline path ----------------
        char* w = (char*)d_ws;
        int*    cnt   = (int*)w;    w += 256;
        ushort* cpF   = (ushort*)w; w += up((size_t)KPAD * 512 * 2);
        float*  c2    = (float*)w;  w += up((size_t)KPAD * 4);
        float*  pb1   = (float*)w;  w += up((size_t)NSPLIT * Ntok * 4);
        float*  pb2   = (float*)w;  w += up((size_t)NSPLIT * Ntok * 4);
        int*    pbi   = (int*)w;    w += up((size_t)NSPLIT * Ntok * 4);
        int*    gidx  = (int*)w;    w += up((size_t)Ntok * 4);
        int*    tlist = (int*)w;    w += up((size_t)Ntok * 4);
        float*  tl    = (float*)w;

        ushort* xpF = (ushort*)d_out;   // 16.8 MB: exact fit in out_tok region

        const int nwav = 32 * (Ntok >> 5) + 32 * NEB + KPAD;

        hipMemsetAsync(cnt, 0, 4, stream);
        p01_pack<<<dim3((nwav + 3) / 4), dim3(256), 0, stream>>>(
            x4, cb4, ridx, xpF, cpF, c2, Ntok, K);
        k1_mfma<<<dim3((Ntok / TMTOK) * NSPLIT), dim3(512), 0, stream>>>(
            xpF, cpF, c2, pb1, pb2, pbi, Ntok);
        k2_combine<<<dim3((Ntok + 255) / 256), dim3(256), 0, stream>>>(
            pb1, pb2, pbi, ridx, gidx, tlist, cnt, Ntok, NSPLIT);
        k_recheck<<<dim3(256), dim3(256), 0, stream>>>(
            x4, cb4, ridx, tlist, cnt, gidx, K);
        k3_gather<<<dim3(gblocks), dim3(256), 0, stream>>>(
            x4, cb4, gidx, (float4*)out, out_idx, tl, Ntok);
        k4_loss<<<dim3(1), dim3(256), 0, stream>>>(tl, out_loss, Ntok, inv_total);
    } else {
        // ---------------- f32 fallback (round-2 proven) ----------------
        const int kpad  = 4096;
        const int kspan = 1024;
        char* w = (char*)d_ws;
        int*   cnt   = (int*)w;    w += 256;
        float* c2    = (float*)w;  w += up((size_t)kpad * 4);
        float* pb1   = (float*)w;  w += up((size_t)4 * Ntok * 4);
        float* pb2   = (float*)w;  w += up((size_t)4 * Ntok * 4);
        int*   pbi   = (int*)w;    w += up((size_t)4 * Ntok * 4);
        int*   gidx  = (int*)w;    w += up((size_t)Ntok * 4);
        int*   tlist = (int*)w;    w += up((size_t)Ntok * 4);
        float* tl    = (float*)w;

        hipMemsetAsync(cnt, 0, 4, stream);
        k0_c2<<<dim3(kpad / 4), dim3(256), 0, stream>>>(cb4, ridx, c2, K, kpad);
        fk1_argmin<<<dim3(Ntok / 128, 4), dim3(256), 0, stream>>>(
            x4, cb4, ridx, c2, pb1, pb2, pbi, Ntok, K, kspan);
        k2_combine<<<dim3((Ntok + 255) / 256), dim3(256), 0, stream>>>(
            pb1, pb2, pbi, ridx, gidx, tlist, cnt, Ntok, 4);
        k_recheck<<<dim3(256), dim3(256), 0, stream>>>(
            x4, cb4, ridx, tlist, cnt, gidx, K);
        k3_gather<<<dim3(gblocks), dim3(256), 0, stream>>>(
            x4, cb4, gidx, (float4*)out, out_idx, tl, Ntok);
        k4_loss<<<dim3(1), dim3(256), 0, stream>>>(tl, out_loss, Ntok, inv_total);
    }
}